// Round 7
// baseline (218.109 us; speedup 1.0000x reference)
//
#include <hip/hip_runtime.h>
#include <hip/hip_bf16.h>

#define S_LEN 2048
#define HDIM  1024
#define NHEADS 16
#define HD    64
#define QKV_STRIDE (S_LEN * 2 * HDIM)   // 4194304 elements per tensor

typedef __attribute__((ext_vector_type(8))) short short8;
typedef __attribute__((ext_vector_type(4))) float float4v;

// cheap bf16 convert: round-half-up (bias ~2^-24 rel, negligible vs bf16 eps)
__device__ __forceinline__ unsigned short f2bf(float f) {
  return (unsigned short)((__builtin_bit_cast(unsigned int, f) + 0x8000u) >> 16);
}
// pack two floats -> two bf16 in one u32 via v_perm_b32 (3 VALU ops)
__device__ __forceinline__ unsigned int pkbf(float a, float b) {
  unsigned int ua = __builtin_bit_cast(unsigned int, a) + 0x8000u;
  unsigned int ub = __builtin_bit_cast(unsigned int, b) + 0x8000u;
  return __builtin_amdgcn_perm(ub, ua, 0x07060302u);  // {ub.hi16, ua.hi16}
}
// pack two floats -> two bf16 in ONE VALU op (RNE). Proven in R1 (passed, same absmax).
__device__ __forceinline__ unsigned int cvtpk(float a, float b) {
  unsigned int r;
  asm("v_cvt_pk_bf16_f32 %0, %1, %2" : "=v"(r) : "v"(a), "v"(b));
  return r;
}

__device__ __forceinline__ void async_copy16(const void* g, void* l) {
  __builtin_amdgcn_global_load_lds((__attribute__((address_space(1))) const void*)g,
                                   (__attribute__((address_space(3))) void*)l, 16, 0, 0);
}

// ---------------- fused prep: cast X (fp32->bf16) + transpose/cast weights ----------------
// blocks [0,4096): X cast, 4 elems/thread. blocks [4096,5120): W transpose tiles.
__global__ void prep_kernel(const float* __restrict__ X, unsigned short* __restrict__ Xb,
                            const float* __restrict__ W0, const float* __restrict__ W1,
                            const float* __restrict__ W2, const float* __restrict__ W3,
                            unsigned short* __restrict__ Wt) {
  __shared__ unsigned short tile[64][72];   // [n_loc][k_loc], padded (trans branch only)
  const int t = threadIdx.x;
  if (blockIdx.x < 4096) {
    int i = blockIdx.x * 256 + t;          // 0 .. 1048575 float4 chunks
    float4 v = ((const float4*)X)[i];
    uint2 o;
    o.x = pkbf(v.x, v.y);
    o.y = pkbf(v.z, v.w);
    ((uint2*)Xb)[i] = o;
    return;
  }
  const int wid = blockIdx.x - 4096;       // 0..1023
  const int z = wid >> 8;                  // 0..3
  const int rem = wid & 255;
  const int n0 = (rem & 15) * 64;
  const int k0 = (rem >> 4) * 64;
  const float* W = (z == 0) ? W0 : (z == 1) ? W1 : (z == 2) ? W2 : W3;
  unsigned short* out = Wt + (size_t)z * HDIM * HDIM;
#pragma unroll
  for (int it = 0; it < 4; ++it) {
    int idx = it * 256 + t;          // 1024 float4 chunks
    int r  = idx >> 4;               // k_loc 0..63
    int c4 = (idx & 15) * 4;         // n_loc
    float4 v = *(const float4*)&W[(size_t)(k0 + r) * HDIM + n0 + c4];
    tile[c4 + 0][r] = f2bf(v.x);
    tile[c4 + 1][r] = f2bf(v.y);
    tile[c4 + 2][r] = f2bf(v.z);
    tile[c4 + 3][r] = f2bf(v.w);
  }
  __syncthreads();
#pragma unroll
  for (int it = 0; it < 4; ++it) {
    int idx = it * 256 + t;
    int r  = idx >> 4;               // n_loc
    int c4 = (idx & 15) * 4;         // k_loc
    ushort4 o;
    o.x = tile[r][c4 + 0]; o.y = tile[r][c4 + 1];
    o.z = tile[r][c4 + 2]; o.w = tile[r][c4 + 3];
    *(ushort4*)&out[(size_t)(n0 + r) * HDIM + k0 + c4] = o;
  }
}

// ---------------- fused QKV GEMM, DOUBLE-BUFFERED (one barrier per K-step) ----------------
// Frozen at R4 state.
__global__ __launch_bounds__(256, 2) void gemm_qkv_kernel(
    const unsigned short* __restrict__ A,
    const unsigned short* __restrict__ Wt,   // 3 B^T matrices, 1M elements apart
    unsigned short* __restrict__ out)
{
  __shared__ unsigned short sA[2 * 128 * 32];      // 16 KB
  __shared__ unsigned short sB[2 * 3 * 64 * 32];   // 24 KB
  const int m0 = blockIdx.x * 128;
  const int n0 = blockIdx.y * 64;
  const int t = threadIdx.x;
  const int lane = t & 63;
  const int w = t >> 6;
  const int wm = w & 1, wn = w >> 1;

  const int sr  = lane >> 2;                  // row within 16
  const int scp = lane & 3;                   // physical chunk
  const int scl = scp ^ ((sr >> 1) & 3);      // logical (global) k-chunk
  const long ga0 = (long)(m0 + 16 * w + sr) * HDIM + scl * 8;
  const long ga1 = ga0 + 64l * HDIM;
  const long gb  = (long)(n0 + 16 * w + sr) * HDIM + scl * 8;

  const int fr = lane & 15;
  const int fq = lane >> 4;
  int offA[4], offB[2];
#pragma unroll
  for (int i = 0; i < 4; ++i) {
    int ra = wm * 64 + i * 16 + fr;
    offA[i] = ra * 32 + (fq ^ ((ra >> 1) & 3)) * 8;
  }
#pragma unroll
  for (int i = 0; i < 2; ++i) {
    int rb = wn * 32 + i * 16 + fr;
    offB[i] = rb * 32 + (fq ^ ((rb >> 1) & 3)) * 8;
  }

  float4v acc[3][4][2] = {};

  // stage K-step ks into buffer ks&1 (5 copies per wave)
  auto stage = [&](int ks) {
    const int kk = ks * 32;
    unsigned short* A0 = &sA[(ks & 1) * 4096 + (16 * w) * 32];
    unsigned short* Bb = &sB[(ks & 1) * 6144 + (16 * w) * 32];
    async_copy16(A + ga0 + kk, A0);
    async_copy16(A + ga1 + kk, A0 + 2048);
#pragma unroll
    for (int z = 0; z < 3; ++z)
      async_copy16(Wt + (long)z * (HDIM * HDIM) + gb + kk, Bb + z * 2048);
  };

  stage(0);
#pragma unroll 2
  for (int ks = 0; ks < 32; ++ks) {
    __syncthreads();                 // vmcnt drain -> tile ks resident
    if (ks < 31) stage(ks + 1);      // in flight during compute below
    const unsigned short* a  = &sA[(ks & 1) * 4096];
    const unsigned short* bb = &sB[(ks & 1) * 6144];
    short8 af[4];
#pragma unroll
    for (int i = 0; i < 4; ++i) af[i] = *(const short8*)&a[offA[i]];
#pragma unroll
    for (int z = 0; z < 3; ++z) {
      short8 b0 = *(const short8*)&bb[z * 2048 + offB[0]];
      short8 b1 = *(const short8*)&bb[z * 2048 + offB[1]];
#pragma unroll
      for (int mi = 0; mi < 4; ++mi) {
        acc[z][mi][0] = __builtin_amdgcn_mfma_f32_16x16x32_bf16(af[mi], b0, acc[z][mi][0], 0, 0, 0);
        acc[z][mi][1] = __builtin_amdgcn_mfma_f32_16x16x32_bf16(af[mi], b1, acc[z][mi][1], 0, 0, 0);
      }
    }
  }

  // ---- epilogues ----
  // z==0 (Q^T, scaled) and z==2 (V^T): packed (b,h,d,s)
#pragma unroll
  for (int z = 0; z < 3; z += 2) {
    const float scle = (z == 0) ? 0.18033688011112042f : 1.0f;
    unsigned short* o = out + (size_t)z * QKV_STRIDE;
#pragma unroll
    for (int mi = 0; mi < 4; ++mi)
#pragma unroll
      for (int ni = 0; ni < 2; ++ni) {
        int m = m0 + wm * 64 + mi * 16 + fq * 4;   // s base (multiple of 4)
        int n = n0 + wn * 32 + ni * 16 + fr;
        int b = m >> 11, s = m & 2047, hh = n >> 6, d = n & 63;
        uint2 pk;
        pk.x = pkbf(acc[z][mi][ni][0] * scle, acc[z][mi][ni][1] * scle);
        pk.y = pkbf(acc[z][mi][ni][2] * scle, acc[z][mi][ni][3] * scle);
        *(uint2*)&o[(((size_t)(b * NHEADS + hh)) * HD + d) * S_LEN + s] = pk;
      }
  }
  // z==1 (K): natural (b,h,s,d) scatter
  {
    unsigned short* o = out + (size_t)QKV_STRIDE;
#pragma unroll
    for (int mi = 0; mi < 4; ++mi)
#pragma unroll
      for (int ni = 0; ni < 2; ++ni)
#pragma unroll
        for (int rg = 0; rg < 4; ++rg) {
          int m = m0 + wm * 64 + mi * 16 + fq * 4 + rg;
          int n = n0 + wn * 32 + ni * 16 + fr;
          int b = m >> 11, s = m & 2047, hh = n >> 6, d = n & 63;
          o[(((size_t)(b * NHEADS + hh)) * S_LEN + s) * HD + d] = f2bf(acc[1][mi][ni][rg]);
        }
  }
}

// ------------- 128x128 bf16 GEMM (output projection), DOUBLE-BUFFERED -------------
// Frozen at R4 state. LDS 2x(8+8) = 32 KB.
__global__ __launch_bounds__(256, 3) void gemm128_kernel(
    const unsigned short* __restrict__ A,
    const unsigned short* __restrict__ Bt,
    float* __restrict__ out)
{
  __shared__ unsigned short sA[2 * 128 * 32];
  __shared__ unsigned short sB[2 * 128 * 32];
  const int m0 = blockIdx.x * 128;
  const int n0 = blockIdx.y * 128;
  const int t = threadIdx.x;
  const int lane = t & 63;
  const int w = t >> 6;
  const int wm = w & 1, wn = w >> 1;

  const int sr  = lane >> 2;                  // row within 16
  const int scp = lane & 3;                   // physical chunk
  const int scl = scp ^ ((sr >> 1) & 3);      // logical (global) k-chunk
  const long ga0 = (long)(m0 + 16 * w + sr) * HDIM + scl * 8;
  const long ga1 = ga0 + 64l * HDIM;
  const long gb0 = (long)(n0 + 16 * w + sr) * HDIM + scl * 8;
  const long gb1 = gb0 + 64l * HDIM;

  const int fr = lane & 15;
  const int fq = lane >> 4;
  int offA[4], offB[4];
#pragma unroll
  for (int i = 0; i < 4; ++i) {
    int ra = wm * 64 + i * 16 + fr;
    offA[i] = ra * 32 + (fq ^ ((ra >> 1) & 3)) * 8;
    int rb = wn * 64 + i * 16 + fr;
    offB[i] = rb * 32 + (fq ^ ((rb >> 1) & 3)) * 8;
  }

  float4v acc[4][4] = {};

  auto stage = [&](int ks) {
    const int kk = ks * 32;
    unsigned short* A0 = &sA[(ks & 1) * 4096 + (16 * w) * 32];
    unsigned short* B0 = &sB[(ks & 1) * 4096 + (16 * w) * 32];
    async_copy16(A + ga0 + kk, A0);
    async_copy16(A + ga1 + kk, A0 + 2048);
    async_copy16(Bt + gb0 + kk, B0);
    async_copy16(Bt + gb1 + kk, B0 + 2048);
  };

  stage(0);
#pragma unroll 2
  for (int ks = 0; ks < 32; ++ks) {
    __syncthreads();                 // vmcnt drain -> tile ks resident
    if (ks < 31) stage(ks + 1);      // overlapped with compute below
    const unsigned short* a = &sA[(ks & 1) * 4096];
    const unsigned short* bp = &sB[(ks & 1) * 4096];
    short8 af[4], bf[4];
#pragma unroll
    for (int i = 0; i < 4; ++i) af[i] = *(const short8*)&a[offA[i]];
#pragma unroll
    for (int i = 0; i < 4; ++i) bf[i] = *(const short8*)&bp[offB[i]];
#pragma unroll
    for (int mi = 0; mi < 4; ++mi)
#pragma unroll
      for (int ni = 0; ni < 4; ++ni)
        acc[mi][ni] = __builtin_amdgcn_mfma_f32_16x16x32_bf16(af[mi], bf[ni], acc[mi][ni], 0, 0, 0);
  }

#pragma unroll
  for (int mi = 0; mi < 4; ++mi)
#pragma unroll
    for (int ni = 0; ni < 4; ++ni)
#pragma unroll
      for (int rg = 0; rg < 4; ++rg) {
        int m = m0 + wm * 64 + mi * 16 + fq * 4 + rg;
        int n = n0 + wn * 64 + ni * 16 + fr;
        out[(size_t)m * HDIM + n] = acc[mi][ni][rg];
      }
}

// stage one 64-k tile (K 8 KB + V^T 8 KB) into buffer (tile&1); 2 DMA copies per wave
__device__ __forceinline__ void stage_tile(char* smem, const unsigned short* Kp,
    const unsigned short* Vtp, size_t base, int tile, int w, int kr, int kc) {
  const int kv = tile * 64;
  char* bufb = smem + (tile & 1) * 16384;
  unsigned short* dK = (unsigned short*)bufb + (w * 8) * 64;
  async_copy16(Kp + base + (size_t)(kv + w * 8 + kr) * HD + ((kc ^ kr) * 8), dK);
  unsigned short* dV = (unsigned short*)(bufb + 8192) + (w * 8) * 64;
  const int d = w * 8 + kr;
  async_copy16(Vtp + base + (size_t)d * S_LEN + kv + ((kc ^ kr) * 8), dV);
}

// ---------------- flash attention: split-k waves, fixed-base softmax, ----------------
// ---------------- BN=64 dbuf staging, ONE barrier per tile, PIPELINED PV ----------------
// R7 deltas (attn is VALU-ISSUE-bound: R5 FETCH -5.6x null, R6 reorder null;
// VALUBusy 46% = ~26us issue, exp2 at quarter-rate is ~14us of it):
//  (a) P-pack via v_cvt_pk_bf16_f32 (1 op/pair, proven in R1) instead of pkbf (3 ops):
//      -32 issue cyc per wave-tile.
//  (b) l-sum via ones-row MFMA: mfma(ones, pf, l_acc) -> sum_k P[k][q] on the 23%-idle
//      matrix pipe; removes 12 VALU adds/tile + the end shuffle reduce. Denominator now
//      uses bf16-rounded P, consistent with the PV numerator.
//  (c) setprio removed (null in R5/R6); unroll 4 for cross-tile scheduling room.
// XCD-aware remap kept (K/V L2-resident). Cross-iteration PV pipelining kept from R6.
__global__ __launch_bounds__(512, 4) void attn_kernel(
    const unsigned short* __restrict__ Qtp,
    const unsigned short* __restrict__ Kp,
    const unsigned short* __restrict__ Vtp,
    const int* __restrict__ mask,
    unsigned short* __restrict__ ctx)
{
  __shared__ __align__(16) char smem[53248];

  // XCD-aware remap: p in [0,512); bh = (p&7)+8*(j>>4), q-tile = j&15, j = p>>3.
  // Bijective: p = (bh&7) + 8*((bh>>3)*16 + qt).
  const int p = blockIdx.x + 16 * blockIdx.y;
  const int j = p >> 3;
  const int bh = (p & 7) + 8 * (j >> 4);
  const int q0 = (j & 15) * 128;

  const int b = bh >> 4;
  const int h = bh & 15;
  const size_t base = (size_t)bh * (S_LEN * HD);
  const int t = threadIdx.x;
  const int lane = t & 63;
  const int w = t >> 6;                        // 0..7
  const int qg = w >> 1;                       // q-group (32 q)
  const int kh = w & 1;                        // k-half (32 k)
  const int fr = lane & 15;
  const int fq = lane >> 4;
  const int kr = lane >> 3, kc = lane & 7;     // staging lane map
  unsigned short* sPw = (unsigned short*)(smem + 32768) + w * (32 * 40);

  // Q fragments (B-operand): 32 q rows, from transposed (b,h,d,s) layout
  short8 qfr[2][2];
#pragma unroll
  for (int q_ = 0; q_ < 2; ++q_)
#pragma unroll
    for (int ks = 0; ks < 2; ++ks)
#pragma unroll
      for (int jj = 0; jj < 8; ++jj)
        qfr[q_][ks][jj] = (short)Qtp[base + (size_t)(ks * 32 + fq * 8 + jj) * S_LEN
                                    + (q0 + qg * 32 + q_ * 16 + fr)];

  // ones A-fragment for the l-sum MFMA (bf16 1.0 = 0x3F80)
  short8 onesv;
#pragma unroll
  for (int jj = 0; jj < 8; ++jj) onesv[jj] = (short)0x3F80;

  float4v o_acc[4][2] = {};                    // [df][q_], partial O^T over this k-half
  float4v l_acc[2] = {};                       // l[q] via ones-MFMA (all rows equal)
  const float4v zero4 = {0.f, 0.f, 0.f, 0.f};
  short8 vf[4];                                // V(t) carried to iteration t+1
  short8 pf[2];                                // P(t-1) fragments

  // mask prefetch for tile 0 (bit k of ballot = mask[kv0+k] != 0)
  int mnext = mask[b * S_LEN + lane];

  // prologue: stage tile 0 into buffer 0
  stage_tile(smem, Kp, Vtp, base, 0, w, kr, kc);

#pragma unroll 4
  for (int it = 0; it < 32; ++it) {
    __syncthreads();   // drains vmcnt -> tile 'it' resident; buffer (it+1)&1 free
    if (it < 31)
      stage_tile(smem, Kp, Vtp, base, it + 1, w, kr, kc);   // in flight during compute

    unsigned long long bal = __ballot(mnext != 0);
    if (it < 31)
      mnext = mask[b * S_LEN + (it + 1) * 64 + lane];       // prefetch next tile's mask

    const unsigned short* sKb  = (const unsigned short*)(smem + (it & 1) * 16384);
    const unsigned short* sVtb = (const unsigned short*)(smem + (it & 1) * 16384 + 8192);

    // early: read P(it-1) fragments; ~120cy LDS latency hides under K reads + QK
    if (it > 0) {
#pragma unroll
      for (int q_ = 0; q_ < 2; ++q_)
        pf[q_] = *(const short8*)&sPw[(q_ * 16 + fr) * 40 + fq * 8];
    }

    // S^T = K · Q^T over this wave's 32-k strip (scores in log2 domain: Q pre-scaled)
    float4v s_acc[2][2];
#pragma unroll
    for (int kf = 0; kf < 2; ++kf) {
      int rk = kh * 32 + kf * 16 + fr;
      short8 k0 = *(const short8*)&sKb[rk * 64 + ((fq ^ (rk & 7)) * 8)];
      short8 k1 = *(const short8*)&sKb[rk * 64 + (((4 + fq) ^ (rk & 7)) * 8)];
#pragma unroll
      for (int q_ = 0; q_ < 2; ++q_) {
        float4v s = __builtin_amdgcn_mfma_f32_16x16x32_bf16(k0, qfr[q_][0], zero4, 0, 0, 0);
        s_acc[kf][q_] = __builtin_amdgcn_mfma_f32_16x16x32_bf16(k1, qfr[q_][1], s, 0, 0, 0);
      }
    }

    // O^T += V^T(it-1) · P^T(it-1); l += ones · P^T(it-1)  (independent of tile it)
    if (it > 0) {
#pragma unroll
      for (int df = 0; df < 4; ++df)
#pragma unroll
        for (int q_ = 0; q_ < 2; ++q_)
          o_acc[df][q_] = __builtin_amdgcn_mfma_f32_16x16x32_bf16(vf[df], pf[q_], o_acc[df][q_], 0, 0, 0);
#pragma unroll
      for (int q_ = 0; q_ < 2; ++q_)
        l_acc[q_] = __builtin_amdgcn_mfma_f32_16x16x32_bf16(onesv, pf[q_], l_acc[q_], 0, 0, 0);
    }

    // exp2 -> (rare) mask zeroing -> pack P^T strip (cvt_pk, 1 op/pair).
    // Strip writes are AFTER the pf reads in program order; wave-level LDS is
    // in-order, so P(it-1) is consumed before being overwritten.
#pragma unroll
    for (int kf = 0; kf < 2; ++kf) {
      unsigned mseg = 0xFu;
      if (bal != ~0ull)                        // wave-uniform slow path
        mseg = (unsigned)(bal >> (kh * 32 + kf * 16 + fq * 4)) & 0xFu;
#pragma unroll
      for (int q_ = 0; q_ < 2; ++q_) {
        float p0 = __builtin_amdgcn_exp2f(s_acc[kf][q_][0]);
        float p1 = __builtin_amdgcn_exp2f(s_acc[kf][q_][1]);
        float p2 = __builtin_amdgcn_exp2f(s_acc[kf][q_][2]);
        float p3 = __builtin_amdgcn_exp2f(s_acc[kf][q_][3]);
        if (bal != ~0ull) {
          p0 = (mseg & 1u) ? p0 : 0.f;
          p1 = (mseg & 2u) ? p1 : 0.f;
          p2 = (mseg & 4u) ? p2 : 0.f;
          p3 = (mseg & 8u) ? p3 : 0.f;
        }
        uint2 pk;
        pk.x = cvtpk(p0, p1);
        pk.y = cvtpk(p2, p3);
        *(uint2*)&sPw[(q_ * 16 + fr) * 40 + (kf * 4 + fq) * 4] = pk;
      }
    }

    // V(it) fragments -> registers, consumed by PV in iteration it+1.
    // Buffer (it&1) is only restaged at it+2, so the carry is safe.
#pragma unroll
    for (int df = 0; df < 4; ++df) {
      int rv = df * 16 + fr;
      vf[df] = *(const short8*)&sVtb[rv * 64 + (((kh * 4 + fq) ^ (fr & 7)) * 8)];
    }
  }

  // drain: PV + l for tile 31
#pragma unroll
  for (int q_ = 0; q_ < 2; ++q_)
    pf[q_] = *(const short8*)&sPw[(q_ * 16 + fr) * 40 + fq * 8];
#pragma unroll
  for (int df = 0; df < 4; ++df)
#pragma unroll
    for (int q_ = 0; q_ < 2; ++q_)
      o_acc[df][q_] = __builtin_amdgcn_mfma_f32_16x16x32_bf16(vf[df], pf[q_], o_acc[df][q_], 0, 0, 0);
#pragma unroll
  for (int q_ = 0; q_ < 2; ++q_)
    l_acc[q_] = __builtin_amdgcn_mfma_f32_16x16x32_bf16(onesv, pf[q_], l_acc[q_], 0, 0, 0);

  // l[q=fr] = l_acc[q_][*]: every row of the ones-MFMA C equals the k-sum -> no shuffles
  float l_lane[2] = { l_acc[0][0], l_acc[1][0] };

  // cross-wave-pair (kh) reduction via LDS.
  // Record: 32 O floats + 2 l floats, stride 34 (136 B). 4 pairs x 64 lanes x 136 B
  // = 34816 B, aliasing the dbuf + wave-0's P strip (all dead after the barrier).
  __syncthreads();   // all waves done with buffers/strips before aliasing
  float* red = (float*)smem;
  float* rec = red + (size_t)(qg * 64 + lane) * 34;
  if (kh) {
#pragma unroll
    for (int df = 0; df < 4; ++df)
#pragma unroll
      for (int q_ = 0; q_ < 2; ++q_) {
        int e = df * 2 + q_;
        *(float2*)&rec[4 * e]     = make_float2(o_acc[df][q_][0], o_acc[df][q_][1]);
        *(float2*)&rec[4 * e + 2] = make_float2(o_acc[df][q_][2], o_acc[df][q_][3]);
      }
    *(float2*)&rec[32] = make_float2(l_lane[0], l_lane[1]);
  }
  __syncthreads();
  if (!kh) {
#pragma unroll
    for (int df = 0; df < 4; ++df)
#pragma unroll
      for (int q_ = 0; q_ < 2; ++q_) {
        int e = df * 2 + q_;
        float2 a = *(float2*)&rec[4 * e];
        float2 c = *(float2*)&rec[4 * e + 2];
        o_acc[df][q_][0] += a.x; o_acc[df][q_][1] += a.y;
        o_acc[df][q_][2] += c.x; o_acc[df][q_][3] += c.y;
      }
    float2 lr = *(float2*)&rec[32];
    float inv_l[2];
    inv_l[0] = 1.0f / (l_lane[0] + lr.x);
    inv_l[1] = 1.0f / (l_lane[1] + lr.y);
    // epilogue: O^T C-layout -> 4 consecutive d per lane -> packed 8B stores
#pragma unroll
    for (int q_ = 0; q_ < 2; ++q_) {
      size_t rowoff = ((size_t)(b * S_LEN + q0 + qg * 32 + q_ * 16 + fr)) * HDIM + h * HD;
#pragma unroll
      for (int df = 0; df < 4; ++df) {
        uint2 pk;
        pk.x = pkbf(o_acc[df][q_][0] * inv_l[q_], o_acc[df][q_][1] * inv_l[q_]);
        pk.y = pkbf(o_acc[df][q_][2] * inv_l[q_], o_acc[df][q_][3] * inv_l[q_]);
        *(uint2*)&ctx[rowoff + df * 16 + fq * 4] = pk;
      }
    }
  }
}

extern "C" void kernel_launch(void* const* d_in, const int* in_sizes, int n_in,
                              void* d_out, int out_size, void* d_ws, size_t ws_size,
                              hipStream_t stream) {
  const float* X  = (const float*)d_in[0];
  const int* mask = (const int*)d_in[1];
  const float* Wq = (const float*)d_in[2];
  const float* Wk = (const float*)d_in[3];
  const float* Wv = (const float*)d_in[4];
  const float* Wo = (const float*)d_in[5];
  float* out = (float*)d_out;

  char* ws = (char*)d_ws;
  // layout (40 MB): [0,8M) Xb then reused as CTX; [8M,16M) Wt x4; [16M,40M) Q^T,K,V^T bf16
  unsigned short* Xb  = (unsigned short*)(ws);
  unsigned short* Wt  = (unsigned short*)(ws + (8u << 20));
  unsigned short* QKV = (unsigned short*)(ws + (16u << 20));
  unsigned short* CTX = (unsigned short*)(ws);   // reuse Xb region (dead after QKV GEMM)

  prep_kernel<<<5120, 256, 0, stream>>>(X, Xb, Wq, Wk, Wv, Wo, Wt);
  gemm_qkv_kernel<<<dim3(32, 16), 256, 0, stream>>>(Xb, Wt, QKV);
  attn_kernel<<<dim3(16, 32), 512, 0, stream>>>(
      QKV, QKV + QKV_STRIDE, QKV + 2 * (size_t)QKV_STRIDE, mask, CTX);
  gemm128_kernel<<<dim3(32, 8), 256, 0, stream>>>(CTX, Wt + (3u << 20), out);
}

// Round 9
// 188.914 us; speedup vs baseline: 1.1545x; 1.1545x over previous
//
#include <hip/hip_runtime.h>
#include <hip/hip_bf16.h>

#define S_LEN 2048
#define HDIM  1024
#define NHEADS 16
#define HD    64
#define QKV_STRIDE (S_LEN * 2 * HDIM)   // 4194304 elements per tensor

typedef __attribute__((ext_vector_type(8))) short short8;
typedef __attribute__((ext_vector_type(4))) float float4v;

// cheap bf16 convert: round-half-up (bias ~2^-24 rel, negligible vs bf16 eps)
__device__ __forceinline__ unsigned short f2bf(float f) {
  return (unsigned short)((__builtin_bit_cast(unsigned int, f) + 0x8000u) >> 16);
}
// pack two floats -> two bf16 in one u32 via v_perm_b32 (3 VALU ops)
__device__ __forceinline__ unsigned int pkbf(float a, float b) {
  unsigned int ua = __builtin_bit_cast(unsigned int, a) + 0x8000u;
  unsigned int ub = __builtin_bit_cast(unsigned int, b) + 0x8000u;
  return __builtin_amdgcn_perm(ub, ua, 0x07060302u);  // {ub.hi16, ua.hi16}
}
// pack two floats -> two bf16 in ONE VALU op (RNE). Numerics proven in R1.
__device__ __forceinline__ unsigned int cvtpk(float a, float b) {
  unsigned int r;
  asm("v_cvt_pk_bf16_f32 %0, %1, %2" : "=v"(r) : "v"(a), "v"(b));
  return r;
}

__device__ __forceinline__ void async_copy16(const void* g, void* l) {
  __builtin_amdgcn_global_load_lds((__attribute__((address_space(1))) const void*)g,
                                   (__attribute__((address_space(3))) void*)l, 16, 0, 0);
}

// ---------------- fused prep: cast X (fp32->bf16) + transpose/cast weights ----------------
// blocks [0,4096): X cast, 4 elems/thread. blocks [4096,5120): W transpose tiles.
__global__ void prep_kernel(const float* __restrict__ X, unsigned short* __restrict__ Xb,
                            const float* __restrict__ W0, const float* __restrict__ W1,
                            const float* __restrict__ W2, const float* __restrict__ W3,
                            unsigned short* __restrict__ Wt) {
  __shared__ unsigned short tile[64][72];   // [n_loc][k_loc], padded (trans branch only)
  const int t = threadIdx.x;
  if (blockIdx.x < 4096) {
    int i = blockIdx.x * 256 + t;          // 0 .. 1048575 float4 chunks
    float4 v = ((const float4*)X)[i];
    uint2 o;
    o.x = pkbf(v.x, v.y);
    o.y = pkbf(v.z, v.w);
    ((uint2*)Xb)[i] = o;
    return;
  }
  const int wid = blockIdx.x - 4096;       // 0..1023
  const int z = wid >> 8;                  // 0..3
  const int rem = wid & 255;
  const int n0 = (rem & 15) * 64;
  const int k0 = (rem >> 4) * 64;
  const float* W = (z == 0) ? W0 : (z == 1) ? W1 : (z == 2) ? W2 : W3;
  unsigned short* out = Wt + (size_t)z * HDIM * HDIM;
#pragma unroll
  for (int it = 0; it < 4; ++it) {
    int idx = it * 256 + t;          // 1024 float4 chunks
    int r  = idx >> 4;               // k_loc 0..63
    int c4 = (idx & 15) * 4;         // n_loc
    float4 v = *(const float4*)&W[(size_t)(k0 + r) * HDIM + n0 + c4];
    tile[c4 + 0][r] = f2bf(v.x);
    tile[c4 + 1][r] = f2bf(v.y);
    tile[c4 + 2][r] = f2bf(v.z);
    tile[c4 + 3][r] = f2bf(v.w);
  }
  __syncthreads();
#pragma unroll
  for (int it = 0; it < 4; ++it) {
    int idx = it * 256 + t;
    int r  = idx >> 4;               // n_loc
    int c4 = (idx & 15) * 4;         // k_loc
    ushort4 o;
    o.x = tile[r][c4 + 0]; o.y = tile[r][c4 + 1];
    o.z = tile[r][c4 + 2]; o.w = tile[r][c4 + 3];
    *(ushort4*)&out[(size_t)(n0 + r) * HDIM + k0 + c4] = o;
  }
}

// ---------------- fused QKV GEMM, 64x64 tile, dbuf, 4 blocks/CU ----------------
// Tile 128x64 -> 64x64; grid 64x16 = 1024 blocks = 4/CU (was 2/CU, grid-limited).
// Latency-bound K-loop gains cross-block TLP: 4 independent barrier groups per CU.
// LDS 32KB dbuf (A 2x4KB + B 2x12KB); acc 3z x 2mi x 2ni = 48 VGPR; (256,4) -> 128 cap.
// Staging/swizzle formulas unchanged (16-row-per-wave granularity).
__global__ __launch_bounds__(256, 4) void gemm_qkv_kernel(
    const unsigned short* __restrict__ A,
    const unsigned short* __restrict__ Wt,   // 3 B^T matrices, 1M elements apart
    unsigned short* __restrict__ out)
{
  __shared__ unsigned short sA[2 * 64 * 32];       // 8 KB
  __shared__ unsigned short sB[2 * 3 * 64 * 32];   // 24 KB
  const int m0 = blockIdx.x * 64;
  const int n0 = blockIdx.y * 64;
  const int t = threadIdx.x;
  const int lane = t & 63;
  const int w = t >> 6;
  const int wm = w & 1, wn = w >> 1;

  const int sr  = lane >> 2;                  // row within 16
  const int scp = lane & 3;                   // physical chunk
  const int scl = scp ^ ((sr >> 1) & 3);      // logical (global) k-chunk
  const long ga0 = (long)(m0 + 16 * w + sr) * HDIM + scl * 8;
  const long gb  = (long)(n0 + 16 * w + sr) * HDIM + scl * 8;

  const int fr = lane & 15;
  const int fq = lane >> 4;
  int offA[2], offB[2];
#pragma unroll
  for (int i = 0; i < 2; ++i) {
    int ra = wm * 32 + i * 16 + fr;
    offA[i] = ra * 32 + (fq ^ ((ra >> 1) & 3)) * 8;
    int rb = wn * 32 + i * 16 + fr;
    offB[i] = rb * 32 + (fq ^ ((rb >> 1) & 3)) * 8;
  }

  float4v acc[3][2][2] = {};

  // stage K-step ks into buffer ks&1 (4 copies per wave)
  auto stage = [&](int ks) {
    const int kk = ks * 32;
    unsigned short* A0 = &sA[(ks & 1) * 2048 + (16 * w) * 32];
    unsigned short* Bb = &sB[(ks & 1) * 6144 + (16 * w) * 32];
    async_copy16(A + ga0 + kk, A0);
#pragma unroll
    for (int z = 0; z < 3; ++z)
      async_copy16(Wt + (long)z * (HDIM * HDIM) + gb + kk, Bb + z * 2048);
  };

  stage(0);
#pragma unroll 2
  for (int ks = 0; ks < 32; ++ks) {
    __syncthreads();                 // vmcnt drain -> tile ks resident
    if (ks < 31) stage(ks + 1);      // in flight during compute below
    const unsigned short* a  = &sA[(ks & 1) * 2048];
    const unsigned short* bb = &sB[(ks & 1) * 6144];
    short8 af[2];
#pragma unroll
    for (int i = 0; i < 2; ++i) af[i] = *(const short8*)&a[offA[i]];
#pragma unroll
    for (int z = 0; z < 3; ++z) {
      short8 b0 = *(const short8*)&bb[z * 2048 + offB[0]];
      short8 b1 = *(const short8*)&bb[z * 2048 + offB[1]];
#pragma unroll
      for (int mi = 0; mi < 2; ++mi) {
        acc[z][mi][0] = __builtin_amdgcn_mfma_f32_16x16x32_bf16(af[mi], b0, acc[z][mi][0], 0, 0, 0);
        acc[z][mi][1] = __builtin_amdgcn_mfma_f32_16x16x32_bf16(af[mi], b1, acc[z][mi][1], 0, 0, 0);
      }
    }
  }

  // ---- epilogues ----
  // z==0 (Q^T, scaled) and z==2 (V^T): packed (b,h,d,s)
#pragma unroll
  for (int z = 0; z < 3; z += 2) {
    const float scle = (z == 0) ? 0.18033688011112042f : 1.0f;
    unsigned short* o = out + (size_t)z * QKV_STRIDE;
#pragma unroll
    for (int mi = 0; mi < 2; ++mi)
#pragma unroll
      for (int ni = 0; ni < 2; ++ni) {
        int m = m0 + wm * 32 + mi * 16 + fq * 4;   // s base (multiple of 4)
        int n = n0 + wn * 32 + ni * 16 + fr;
        int b = m >> 11, s = m & 2047, hh = n >> 6, d = n & 63;
        uint2 pk;
        pk.x = pkbf(acc[z][mi][ni][0] * scle, acc[z][mi][ni][1] * scle);
        pk.y = pkbf(acc[z][mi][ni][2] * scle, acc[z][mi][ni][3] * scle);
        *(uint2*)&o[(((size_t)(b * NHEADS + hh)) * HD + d) * S_LEN + s] = pk;
      }
  }
  // z==1 (K): natural (b,h,s,d) scatter
  {
    unsigned short* o = out + (size_t)QKV_STRIDE;
#pragma unroll
    for (int mi = 0; mi < 2; ++mi)
#pragma unroll
      for (int ni = 0; ni < 2; ++ni)
#pragma unroll
        for (int rg = 0; rg < 4; ++rg) {
          int m = m0 + wm * 32 + mi * 16 + fq * 4 + rg;
          int n = n0 + wn * 32 + ni * 16 + fr;
          int b = m >> 11, s = m & 2047, hh = n >> 6, d = n & 63;
          o[(((size_t)(b * NHEADS + hh)) * S_LEN + s) * HD + d] = f2bf(acc[1][mi][ni][rg]);
        }
  }
}

// ------------- 64x64 bf16 GEMM (output projection), dbuf, 4 blocks/CU -------------
// Tile 128x128 -> 64x64; grid 64x16 = 1024 = 4/CU (was 256 = 1/CU, the worst
// TLP in the whole pipeline). LDS 16KB dbuf; acc 2x2x4 = 16 VGPR.
__global__ __launch_bounds__(256, 4) void gemm128_kernel(
    const unsigned short* __restrict__ A,
    const unsigned short* __restrict__ Bt,
    float* __restrict__ out)
{
  __shared__ unsigned short sA[2 * 64 * 32];   // 8 KB
  __shared__ unsigned short sB[2 * 64 * 32];   // 8 KB
  const int m0 = blockIdx.x * 64;
  const int n0 = blockIdx.y * 64;
  const int t = threadIdx.x;
  const int lane = t & 63;
  const int w = t >> 6;
  const int wm = w & 1, wn = w >> 1;

  const int sr  = lane >> 2;                  // row within 16
  const int scp = lane & 3;                   // physical chunk
  const int scl = scp ^ ((sr >> 1) & 3);      // logical (global) k-chunk
  const long ga0 = (long)(m0 + 16 * w + sr) * HDIM + scl * 8;
  const long gb0 = (long)(n0 + 16 * w + sr) * HDIM + scl * 8;

  const int fr = lane & 15;
  const int fq = lane >> 4;
  int offA[2], offB[2];
#pragma unroll
  for (int i = 0; i < 2; ++i) {
    int ra = wm * 32 + i * 16 + fr;
    offA[i] = ra * 32 + (fq ^ ((ra >> 1) & 3)) * 8;
    int rb = wn * 32 + i * 16 + fr;
    offB[i] = rb * 32 + (fq ^ ((rb >> 1) & 3)) * 8;
  }

  float4v acc[2][2] = {};

  auto stage = [&](int ks) {
    const int kk = ks * 32;
    unsigned short* A0 = &sA[(ks & 1) * 2048 + (16 * w) * 32];
    unsigned short* B0 = &sB[(ks & 1) * 2048 + (16 * w) * 32];
    async_copy16(A + ga0 + kk, A0);
    async_copy16(Bt + gb0 + kk, B0);
  };

  stage(0);
#pragma unroll 2
  for (int ks = 0; ks < 32; ++ks) {
    __syncthreads();                 // vmcnt drain -> tile ks resident
    if (ks < 31) stage(ks + 1);      // overlapped with compute below
    const unsigned short* a = &sA[(ks & 1) * 2048];
    const unsigned short* bp = &sB[(ks & 1) * 2048];
    short8 af[2], bf[2];
#pragma unroll
    for (int i = 0; i < 2; ++i) af[i] = *(const short8*)&a[offA[i]];
#pragma unroll
    for (int i = 0; i < 2; ++i) bf[i] = *(const short8*)&bp[offB[i]];
#pragma unroll
    for (int mi = 0; mi < 2; ++mi)
#pragma unroll
      for (int ni = 0; ni < 2; ++ni)
        acc[mi][ni] = __builtin_amdgcn_mfma_f32_16x16x32_bf16(af[mi], bf[ni], acc[mi][ni], 0, 0, 0);
  }

#pragma unroll
  for (int mi = 0; mi < 2; ++mi)
#pragma unroll
    for (int ni = 0; ni < 2; ++ni)
#pragma unroll
      for (int rg = 0; rg < 4; ++rg) {
        int m = m0 + wm * 32 + mi * 16 + fq * 4 + rg;
        int n = n0 + wn * 32 + ni * 16 + fr;
        out[(size_t)m * HDIM + n] = acc[mi][ni][rg];
      }
}

// stage one 64-k tile (K 8 KB + V^T 8 KB) into buffer (tile&1); 2 DMA copies per wave
__device__ __forceinline__ void stage_tile(char* smem, const unsigned short* Kp,
    const unsigned short* Vtp, size_t base, int tile, int w, int kr, int kc) {
  const int kv = tile * 64;
  char* bufb = smem + (tile & 1) * 16384;
  unsigned short* dK = (unsigned short*)bufb + (w * 8) * 64;
  async_copy16(Kp + base + (size_t)(kv + w * 8 + kr) * HD + ((kc ^ kr) * 8), dK);
  unsigned short* dV = (unsigned short*)(bufb + 8192) + (w * 8) * 64;
  const int d = w * 8 + kr;
  async_copy16(Vtp + base + (size_t)d * S_LEN + kv + ((kc ^ kr) * 8), dV);
}

// ---------------- flash attention: split-k waves, fixed-base softmax, ----------------
// ---------------- BN=64 double-buffered staging, ONE barrier per tile ----------------
// R5 structure (R2 + XCD remap, 55.6us verified) + R1-proven cvt_pk P-pack.
// setprio dropped (null in R5/R6). XCD remap kept (FETCH 70->12.4MB, K/V L2-resident).
__global__ __launch_bounds__(512, 4) void attn_kernel(
    const unsigned short* __restrict__ Qtp,
    const unsigned short* __restrict__ Kp,
    const unsigned short* __restrict__ Vtp,
    const int* __restrict__ mask,
    unsigned short* __restrict__ ctx)
{
  __shared__ __align__(16) char smem[53248];

  // XCD-aware remap: p in [0,512); bh = (p&7)+8*(j>>4), q-tile = j&15, j = p>>3.
  // Bijective: p = (bh&7) + 8*((bh>>3)*16 + qt).
  const int p = blockIdx.x + 16 * blockIdx.y;
  const int j = p >> 3;
  const int bh = (p & 7) + 8 * (j >> 4);
  const int q0 = (j & 15) * 128;

  const int b = bh >> 4;
  const int h = bh & 15;
  const size_t base = (size_t)bh * (S_LEN * HD);
  const int t = threadIdx.x;
  const int lane = t & 63;
  const int w = t >> 6;                        // 0..7
  const int qg = w >> 1;                       // q-group (32 q)
  const int kh = w & 1;                        // k-half (32 k)
  const int fr = lane & 15;
  const int fq = lane >> 4;
  const int kr = lane >> 3, kc = lane & 7;     // staging lane map
  unsigned short* sPw = (unsigned short*)(smem + 32768) + w * (32 * 40);

  // Q fragments (B-operand): 32 q rows, from transposed (b,h,d,s) layout
  short8 qfr[2][2];
#pragma unroll
  for (int q_ = 0; q_ < 2; ++q_)
#pragma unroll
    for (int ks = 0; ks < 2; ++ks)
#pragma unroll
      for (int jj = 0; jj < 8; ++jj)
        qfr[q_][ks][jj] = (short)Qtp[base + (size_t)(ks * 32 + fq * 8 + jj) * S_LEN
                                    + (q0 + qg * 32 + q_ * 16 + fr)];

  float l_lane[2] = {0.f, 0.f};
  float4v o_acc[4][2] = {};                    // [df][q_], partial O^T over this k-half
  const float4v zero4 = {0.f, 0.f, 0.f, 0.f};

  // mask prefetch for tile 0 (bit k of ballot = mask[kv0+k] != 0)
  int mnext = mask[b * S_LEN + lane];

  // prologue: stage tile 0 into buffer 0
  stage_tile(smem, Kp, Vtp, base, 0, w, kr, kc);

#pragma unroll 2
  for (int it = 0; it < 32; ++it) {
    __syncthreads();   // drains vmcnt -> tile 'it' resident; buffer (it+1)&1 free
    if (it < 31)
      stage_tile(smem, Kp, Vtp, base, it + 1, w, kr, kc);   // in flight during compute

    unsigned long long bal = __ballot(mnext != 0);
    if (it < 31)
      mnext = mask[b * S_LEN + (it + 1) * 64 + lane];       // prefetch next tile's mask

    const unsigned short* sKb  = (const unsigned short*)(smem + (it & 1) * 16384);
    const unsigned short* sVtb = (const unsigned short*)(smem + (it & 1) * 16384 + 8192);

    // S^T = K · Q^T over this wave's 32-k strip (scores in log2 domain: Q pre-scaled)
    float4v s_acc[2][2];
#pragma unroll
    for (int kf = 0; kf < 2; ++kf) {
      int rk = kh * 32 + kf * 16 + fr;
      short8 k0 = *(const short8*)&sKb[rk * 64 + ((fq ^ (rk & 7)) * 8)];
      short8 k1 = *(const short8*)&sKb[rk * 64 + (((4 + fq) ^ (rk & 7)) * 8)];
#pragma unroll
      for (int q_ = 0; q_ < 2; ++q_) {
        float4v s = __builtin_amdgcn_mfma_f32_16x16x32_bf16(k0, qfr[q_][0], zero4, 0, 0, 0);
        s_acc[kf][q_] = __builtin_amdgcn_mfma_f32_16x16x32_bf16(k1, qfr[q_][1], s, 0, 0, 0);
      }
    }

    // V fragments early: LDS latency overlaps the softmax VALU below
    short8 vf[4];
#pragma unroll
    for (int df = 0; df < 4; ++df) {
      int rv = df * 16 + fr;
      vf[df] = *(const short8*)&sVtb[rv * 64 + (((kh * 4 + fq) ^ (fr & 7)) * 8)];
    }

    // exp2 -> (rare) mask zeroing -> pack P^T strip (cvt_pk) -> per-lane l partials
#pragma unroll
    for (int kf = 0; kf < 2; ++kf) {
      unsigned mseg = 0xFu;
      if (bal != ~0ull)                        // wave-uniform slow path
        mseg = (unsigned)(bal >> (kh * 32 + kf * 16 + fq * 4)) & 0xFu;
#pragma unroll
      for (int q_ = 0; q_ < 2; ++q_) {
        float p0 = __builtin_amdgcn_exp2f(s_acc[kf][q_][0]);
        float p1 = __builtin_amdgcn_exp2f(s_acc[kf][q_][1]);
        float p2 = __builtin_amdgcn_exp2f(s_acc[kf][q_][2]);
        float p3 = __builtin_amdgcn_exp2f(s_acc[kf][q_][3]);
        if (bal != ~0ull) {
          p0 = (mseg & 1u) ? p0 : 0.f;
          p1 = (mseg & 2u) ? p1 : 0.f;
          p2 = (mseg & 4u) ? p2 : 0.f;
          p3 = (mseg & 8u) ? p3 : 0.f;
        }
        l_lane[q_] += (p0 + p1) + (p2 + p3);
        uint2 pk;
        pk.x = cvtpk(p0, p1);
        pk.y = cvtpk(p2, p3);
        *(uint2*)&sPw[(q_ * 16 + fr) * 40 + (kf * 4 + fq) * 4] = pk;
      }
    }
    // no barrier: sP strip is per-wave; LDS ops are in-order within a wave

    // O^T += V^T · P^T over this wave's 32-k strip (single k-step)
    short8 pf[2];
#pragma unroll
    for (int q_ = 0; q_ < 2; ++q_)
      pf[q_] = *(const short8*)&sPw[(q_ * 16 + fr) * 40 + fq * 8];
#pragma unroll
    for (int df = 0; df < 4; ++df)
#pragma unroll
      for (int q_ = 0; q_ < 2; ++q_)
        o_acc[df][q_] = __builtin_amdgcn_mfma_f32_16x16x32_bf16(vf[df], pf[q_], o_acc[df][q_], 0, 0, 0);
  }

  // reduce l over fq within the wave
#pragma unroll
  for (int q_ = 0; q_ < 2; ++q_) {
    l_lane[q_] += __shfl_xor(l_lane[q_], 16);
    l_lane[q_] += __shfl_xor(l_lane[q_], 32);
  }

  // cross-wave-pair (kh) reduction via LDS.
  // Record: 32 O floats + 2 l floats, stride 34 (136 B). 4 pairs x 64 lanes x 136 B
  // = 34816 B, aliasing the dbuf + wave-0's P strip (all dead after the barrier).
  __syncthreads();   // all waves done with buffers/strips before aliasing
  float* red = (float*)smem;
  float* rec = red + (size_t)(qg * 64 + lane) * 34;
  if (kh) {
#pragma unroll
    for (int df = 0; df < 4; ++df)
#pragma unroll
      for (int q_ = 0; q_ < 2; ++q_) {
        int e = df * 2 + q_;
        *(float2*)&rec[4 * e]     = make_float2(o_acc[df][q_][0], o_acc[df][q_][1]);
        *(float2*)&rec[4 * e + 2] = make_float2(o_acc[df][q_][2], o_acc[df][q_][3]);
      }
    *(float2*)&rec[32] = make_float2(l_lane[0], l_lane[1]);
  }
  __syncthreads();
  if (!kh) {
#pragma unroll
    for (int df = 0; df < 4; ++df)
#pragma unroll
      for (int q_ = 0; q_ < 2; ++q_) {
        int e = df * 2 + q_;
        float2 a = *(float2*)&rec[4 * e];
        float2 c = *(float2*)&rec[4 * e + 2];
        o_acc[df][q_][0] += a.x; o_acc[df][q_][1] += a.y;
        o_acc[df][q_][2] += c.x; o_acc[df][q_][3] += c.y;
      }
    float2 lr = *(float2*)&rec[32];
    float inv_l[2];
    inv_l[0] = 1.0f / (l_lane[0] + lr.x);
    inv_l[1] = 1.0f / (l_lane[1] + lr.y);
    // epilogue: O^T C-layout -> 4 consecutive d per lane -> packed 8B stores
#pragma unroll
    for (int q_ = 0; q_ < 2; ++q_) {
      size_t rowoff = ((size_t)(b * S_LEN + q0 + qg * 32 + q_ * 16 + fr)) * HDIM + h * HD;
#pragma unroll
      for (int df = 0; df < 4; ++df) {
        uint2 pk;
        pk.x = pkbf(o_acc[df][q_][0] * inv_l[q_], o_acc[df][q_][1] * inv_l[q_]);
        pk.y = pkbf(o_acc[df][q_][2] * inv_l[q_], o_acc[df][q_][3] * inv_l[q_]);
        *(uint2*)&ctx[rowoff + df * 16 + fq * 4] = pk;
      }
    }
  }
}

extern "C" void kernel_launch(void* const* d_in, const int* in_sizes, int n_in,
                              void* d_out, int out_size, void* d_ws, size_t ws_size,
                              hipStream_t stream) {
  const float* X  = (const float*)d_in[0];
  const int* mask = (const int*)d_in[1];
  const float* Wq = (const float*)d_in[2];
  const float* Wk = (const float*)d_in[3];
  const float* Wv = (const float*)d_in[4];
  const float* Wo = (const float*)d_in[5];
  float* out = (float*)d_out;

  char* ws = (char*)d_ws;
  // layout (40 MB): [0,8M) Xb then reused as CTX; [8M,16M) Wt x4; [16M,40M) Q^T,K,V^T bf16
  unsigned short* Xb  = (unsigned short*)(ws);
  unsigned short* Wt  = (unsigned short*)(ws + (8u << 20));
  unsigned short* QKV = (unsigned short*)(ws + (16u << 20));
  unsigned short* CTX = (unsigned short*)(ws);   // reuse Xb region (dead after QKV GEMM)

  prep_kernel<<<5120, 256, 0, stream>>>(X, Xb, Wq, Wk, Wv, Wo, Wt);
  gemm_qkv_kernel<<<dim3(64, 16), 256, 0, stream>>>(Xb, Wt, QKV);
  attn_kernel<<<dim3(16, 32), 512, 0, stream>>>(
      QKV, QKV + QKV_STRIDE, QKV + 2 * (size_t)QKV_STRIDE, mask, CTX);
  gemm128_kernel<<<dim3(64, 16), 256, 0, stream>>>(CTX, Wt + (3u << 20), out);
}

// Round 11
// 185.986 us; speedup vs baseline: 1.1727x; 1.0157x over previous
//
#include <hip/hip_runtime.h>
#include <hip/hip_bf16.h>

#define S_LEN 2048
#define HDIM  1024
#define NHEADS 16
#define HD    64
#define QKV_STRIDE (S_LEN * 2 * HDIM)   // 4194304 elements per tensor

typedef __attribute__((ext_vector_type(8))) short short8;
typedef __attribute__((ext_vector_type(4))) float float4v;

// cheap bf16 convert: round-half-up (bias ~2^-24 rel, negligible vs bf16 eps)
__device__ __forceinline__ unsigned short f2bf(float f) {
  return (unsigned short)((__builtin_bit_cast(unsigned int, f) + 0x8000u) >> 16);
}
// pack two floats -> two bf16 in one u32 via v_perm_b32 (3 VALU ops)
__device__ __forceinline__ unsigned int pkbf(float a, float b) {
  unsigned int ua = __builtin_bit_cast(unsigned int, a) + 0x8000u;
  unsigned int ub = __builtin_bit_cast(unsigned int, b) + 0x8000u;
  return __builtin_amdgcn_perm(ub, ua, 0x07060302u);  // {ub.hi16, ua.hi16}
}
// pack two floats -> two bf16 in ONE VALU op (RNE). Numerics proven in R1/R9.
__device__ __forceinline__ unsigned int cvtpk(float a, float b) {
  unsigned int r;
  asm("v_cvt_pk_bf16_f32 %0, %1, %2" : "=v"(r) : "v"(a), "v"(b));
  return r;
}

__device__ __forceinline__ void async_copy16(const void* g, void* l) {
  __builtin_amdgcn_global_load_lds((__attribute__((address_space(1))) const void*)g,
                                   (__attribute__((address_space(3))) void*)l, 16, 0, 0);
}

// ---------------- fused prep: cast X (fp32->bf16) + transpose/cast weights ----------------
// blocks [0,4096): X cast, 4 elems/thread. blocks [4096,5120): W transpose tiles.
__global__ void prep_kernel(const float* __restrict__ X, unsigned short* __restrict__ Xb,
                            const float* __restrict__ W0, const float* __restrict__ W1,
                            const float* __restrict__ W2, const float* __restrict__ W3,
                            unsigned short* __restrict__ Wt) {
  __shared__ unsigned short tile[64][72];   // [n_loc][k_loc], padded (trans branch only)
  const int t = threadIdx.x;
  if (blockIdx.x < 4096) {
    int i = blockIdx.x * 256 + t;          // 0 .. 1048575 float4 chunks
    float4 v = ((const float4*)X)[i];
    uint2 o;
    o.x = pkbf(v.x, v.y);
    o.y = pkbf(v.z, v.w);
    ((uint2*)Xb)[i] = o;
    return;
  }
  const int wid = blockIdx.x - 4096;       // 0..1023
  const int z = wid >> 8;                  // 0..3
  const int rem = wid & 255;
  const int n0 = (rem & 15) * 64;
  const int k0 = (rem >> 4) * 64;
  const float* W = (z == 0) ? W0 : (z == 1) ? W1 : (z == 2) ? W2 : W3;
  unsigned short* out = Wt + (size_t)z * HDIM * HDIM;
#pragma unroll
  for (int it = 0; it < 4; ++it) {
    int idx = it * 256 + t;          // 1024 float4 chunks
    int r  = idx >> 4;               // k_loc 0..63
    int c4 = (idx & 15) * 4;         // n_loc
    float4 v = *(const float4*)&W[(size_t)(k0 + r) * HDIM + n0 + c4];
    tile[c4 + 0][r] = f2bf(v.x);
    tile[c4 + 1][r] = f2bf(v.y);
    tile[c4 + 2][r] = f2bf(v.z);
    tile[c4 + 3][r] = f2bf(v.w);
  }
  __syncthreads();
#pragma unroll
  for (int it = 0; it < 4; ++it) {
    int idx = it * 256 + t;
    int r  = idx >> 4;               // n_loc
    int c4 = (idx & 15) * 4;         // k_loc
    ushort4 o;
    o.x = tile[r][c4 + 0]; o.y = tile[r][c4 + 1];
    o.z = tile[r][c4 + 2]; o.w = tile[r][c4 + 3];
    *(ushort4*)&out[(size_t)(n0 + r) * HDIM + k0 + c4] = o;
  }
}

// ---------------- fused QKV GEMM, 128x64 tile, DOUBLE-BUFFERED (R4-verified) ----------------
// stage(ks+1) into the other buffer AFTER the barrier, compute buf ks&1; copies drain
// at the NEXT barrier, a full compute phase later. Residual-best GEMM config (R2-R6:
// 133-134us vs 64^2 tiles' 137us in R9 -- 128-tile wins ~3us net).
__global__ __launch_bounds__(256, 2) void gemm_qkv_kernel(
    const unsigned short* __restrict__ A,
    const unsigned short* __restrict__ Wt,   // 3 B^T matrices, 1M elements apart
    unsigned short* __restrict__ out)
{
  __shared__ unsigned short sA[2 * 128 * 32];      // 16 KB
  __shared__ unsigned short sB[2 * 3 * 64 * 32];   // 24 KB
  const int m0 = blockIdx.x * 128;
  const int n0 = blockIdx.y * 64;
  const int t = threadIdx.x;
  const int lane = t & 63;
  const int w = t >> 6;
  const int wm = w & 1, wn = w >> 1;

  const int sr  = lane >> 2;                  // row within 16
  const int scp = lane & 3;                   // physical chunk
  const int scl = scp ^ ((sr >> 1) & 3);      // logical (global) k-chunk
  const long ga0 = (long)(m0 + 16 * w + sr) * HDIM + scl * 8;
  const long ga1 = ga0 + 64l * HDIM;
  const long gb  = (long)(n0 + 16 * w + sr) * HDIM + scl * 8;

  const int fr = lane & 15;
  const int fq = lane >> 4;
  int offA[4], offB[2];
#pragma unroll
  for (int i = 0; i < 4; ++i) {
    int ra = wm * 64 + i * 16 + fr;
    offA[i] = ra * 32 + (fq ^ ((ra >> 1) & 3)) * 8;
  }
#pragma unroll
  for (int i = 0; i < 2; ++i) {
    int rb = wn * 32 + i * 16 + fr;
    offB[i] = rb * 32 + (fq ^ ((rb >> 1) & 3)) * 8;
  }

  float4v acc[3][4][2] = {};

  // stage K-step ks into buffer ks&1 (5 copies per wave)
  auto stage = [&](int ks) {
    const int kk = ks * 32;
    unsigned short* A0 = &sA[(ks & 1) * 4096 + (16 * w) * 32];
    unsigned short* Bb = &sB[(ks & 1) * 6144 + (16 * w) * 32];
    async_copy16(A + ga0 + kk, A0);
    async_copy16(A + ga1 + kk, A0 + 2048);
#pragma unroll
    for (int z = 0; z < 3; ++z)
      async_copy16(Wt + (long)z * (HDIM * HDIM) + gb + kk, Bb + z * 2048);
  };

  stage(0);
#pragma unroll 2
  for (int ks = 0; ks < 32; ++ks) {
    __syncthreads();                 // vmcnt drain -> tile ks resident
    if (ks < 31) stage(ks + 1);      // in flight during compute below
    const unsigned short* a  = &sA[(ks & 1) * 4096];
    const unsigned short* bb = &sB[(ks & 1) * 6144];
    short8 af[4];
#pragma unroll
    for (int i = 0; i < 4; ++i) af[i] = *(const short8*)&a[offA[i]];
#pragma unroll
    for (int z = 0; z < 3; ++z) {
      short8 b0 = *(const short8*)&bb[z * 2048 + offB[0]];
      short8 b1 = *(const short8*)&bb[z * 2048 + offB[1]];
#pragma unroll
      for (int mi = 0; mi < 4; ++mi) {
        acc[z][mi][0] = __builtin_amdgcn_mfma_f32_16x16x32_bf16(af[mi], b0, acc[z][mi][0], 0, 0, 0);
        acc[z][mi][1] = __builtin_amdgcn_mfma_f32_16x16x32_bf16(af[mi], b1, acc[z][mi][1], 0, 0, 0);
      }
    }
  }

  // ---- epilogues ----
  // z==0 (Q^T, scaled) and z==2 (V^T): packed (b,h,d,s)
#pragma unroll
  for (int z = 0; z < 3; z += 2) {
    const float scle = (z == 0) ? 0.18033688011112042f : 1.0f;
    unsigned short* o = out + (size_t)z * QKV_STRIDE;
#pragma unroll
    for (int mi = 0; mi < 4; ++mi)
#pragma unroll
      for (int ni = 0; ni < 2; ++ni) {
        int m = m0 + wm * 64 + mi * 16 + fq * 4;   // s base (multiple of 4)
        int n = n0 + wn * 32 + ni * 16 + fr;
        int b = m >> 11, s = m & 2047, hh = n >> 6, d = n & 63;
        uint2 pk;
        pk.x = pkbf(acc[z][mi][ni][0] * scle, acc[z][mi][ni][1] * scle);
        pk.y = pkbf(acc[z][mi][ni][2] * scle, acc[z][mi][ni][3] * scle);
        *(uint2*)&o[(((size_t)(b * NHEADS + hh)) * HD + d) * S_LEN + s] = pk;
      }
  }
  // z==1 (K): natural (b,h,s,d) scatter
  {
    unsigned short* o = out + (size_t)QKV_STRIDE;
#pragma unroll
    for (int mi = 0; mi < 4; ++mi)
#pragma unroll
      for (int ni = 0; ni < 2; ++ni)
#pragma unroll
        for (int rg = 0; rg < 4; ++rg) {
          int m = m0 + wm * 64 + mi * 16 + fq * 4 + rg;
          int n = n0 + wn * 32 + ni * 16 + fr;
          int b = m >> 11, s = m & 2047, hh = n >> 6, d = n & 63;
          o[(((size_t)(b * NHEADS + hh)) * S_LEN + s) * HD + d] = f2bf(acc[1][mi][ni][rg]);
        }
  }
}

// ------------- 128x128 bf16 GEMM (output projection), DOUBLE-BUFFERED (R4-verified) -------------
__global__ __launch_bounds__(256, 3) void gemm128_kernel(
    const unsigned short* __restrict__ A,
    const unsigned short* __restrict__ Bt,
    float* __restrict__ out)
{
  __shared__ unsigned short sA[2 * 128 * 32];
  __shared__ unsigned short sB[2 * 128 * 32];
  const int m0 = blockIdx.x * 128;
  const int n0 = blockIdx.y * 128;
  const int t = threadIdx.x;
  const int lane = t & 63;
  const int w = t >> 6;
  const int wm = w & 1, wn = w >> 1;

  const int sr  = lane >> 2;                  // row within 16
  const int scp = lane & 3;                   // physical chunk
  const int scl = scp ^ ((sr >> 1) & 3);      // logical (global) k-chunk
  const long ga0 = (long)(m0 + 16 * w + sr) * HDIM + scl * 8;
  const long ga1 = ga0 + 64l * HDIM;
  const long gb0 = (long)(n0 + 16 * w + sr) * HDIM + scl * 8;
  const long gb1 = gb0 + 64l * HDIM;

  const int fr = lane & 15;
  const int fq = lane >> 4;
  int offA[4], offB[4];
#pragma unroll
  for (int i = 0; i < 4; ++i) {
    int ra = wm * 64 + i * 16 + fr;
    offA[i] = ra * 32 + (fq ^ ((ra >> 1) & 3)) * 8;
    int rb = wn * 64 + i * 16 + fr;
    offB[i] = rb * 32 + (fq ^ ((rb >> 1) & 3)) * 8;
  }

  float4v acc[4][4] = {};

  auto stage = [&](int ks) {
    const int kk = ks * 32;
    unsigned short* A0 = &sA[(ks & 1) * 4096 + (16 * w) * 32];
    unsigned short* B0 = &sB[(ks & 1) * 4096 + (16 * w) * 32];
    async_copy16(A + ga0 + kk, A0);
    async_copy16(A + ga1 + kk, A0 + 2048);
    async_copy16(Bt + gb0 + kk, B0);
    async_copy16(Bt + gb1 + kk, B0 + 2048);
  };

  stage(0);
#pragma unroll 2
  for (int ks = 0; ks < 32; ++ks) {
    __syncthreads();                 // vmcnt drain -> tile ks resident
    if (ks < 31) stage(ks + 1);      // overlapped with compute below
    const unsigned short* a = &sA[(ks & 1) * 4096];
    const unsigned short* bp = &sB[(ks & 1) * 4096];
    short8 af[4], bf[4];
#pragma unroll
    for (int i = 0; i < 4; ++i) af[i] = *(const short8*)&a[offA[i]];
#pragma unroll
    for (int i = 0; i < 4; ++i) bf[i] = *(const short8*)&bp[offB[i]];
#pragma unroll
    for (int mi = 0; mi < 4; ++mi)
#pragma unroll
      for (int ni = 0; ni < 4; ++ni)
        acc[mi][ni] = __builtin_amdgcn_mfma_f32_16x16x32_bf16(af[mi], bf[ni], acc[mi][ni], 0, 0, 0);
  }

#pragma unroll
  for (int mi = 0; mi < 4; ++mi)
#pragma unroll
    for (int ni = 0; ni < 4; ++ni)
#pragma unroll
      for (int rg = 0; rg < 4; ++rg) {
        int m = m0 + wm * 64 + mi * 16 + fq * 4 + rg;
        int n = n0 + wn * 64 + ni * 16 + fr;
        out[(size_t)m * HDIM + n] = acc[mi][ni][rg];
      }
}

// stage one 64-k tile (K 8 KB + V^T 8 KB) into buffer (tile&1); 2 DMA copies per wave
__device__ __forceinline__ void stage_tile(char* smem, const unsigned short* Kp,
    const unsigned short* Vtp, size_t base, int tile, int w, int kr, int kc) {
  const int kv = tile * 64;
  char* bufb = smem + (tile & 1) * 16384;
  unsigned short* dK = (unsigned short*)bufb + (w * 8) * 64;
  async_copy16(Kp + base + (size_t)(kv + w * 8 + kr) * HD + ((kc ^ kr) * 8), dK);
  unsigned short* dV = (unsigned short*)(bufb + 8192) + (w * 8) * 64;
  const int d = w * 8 + kr;
  async_copy16(Vtp + base + (size_t)d * S_LEN + kv + ((kc ^ kr) * 8), dV);
}

// ---------------- flash attention: split-k waves, fixed-base softmax, ----------------
// ---------------- BN=64 double-buffered staging, ONE barrier per tile ----------------
// R9-exact attn (best verified: 51.8us, absmax 2.75e-4). R10's 64-q restructure
// failed correctness (small distributed error, cause unidentified) -> reverted per
// rigor discipline. Kept: XCD remap (FETCH 70->12.4MB), cvt_pk P-pack (-4us, R9).
__global__ __launch_bounds__(512, 4) void attn_kernel(
    const unsigned short* __restrict__ Qtp,
    const unsigned short* __restrict__ Kp,
    const unsigned short* __restrict__ Vtp,
    const int* __restrict__ mask,
    unsigned short* __restrict__ ctx)
{
  __shared__ __align__(16) char smem[53248];

  // XCD-aware remap: p in [0,512); bh = (p&7)+8*(j>>4), q-tile = j&15, j = p>>3.
  // Bijective: p = (bh&7) + 8*((bh>>3)*16 + qt).
  const int p = blockIdx.x + 16 * blockIdx.y;
  const int j = p >> 3;
  const int bh = (p & 7) + 8 * (j >> 4);
  const int q0 = (j & 15) * 128;

  const int b = bh >> 4;
  const int h = bh & 15;
  const size_t base = (size_t)bh * (S_LEN * HD);
  const int t = threadIdx.x;
  const int lane = t & 63;
  const int w = t >> 6;                        // 0..7
  const int qg = w >> 1;                       // q-group (32 q)
  const int kh = w & 1;                        // k-half (32 k)
  const int fr = lane & 15;
  const int fq = lane >> 4;
  const int kr = lane >> 3, kc = lane & 7;     // staging lane map
  unsigned short* sPw = (unsigned short*)(smem + 32768) + w * (32 * 40);

  // Q fragments (B-operand): 32 q rows, from transposed (b,h,d,s) layout
  short8 qfr[2][2];
#pragma unroll
  for (int q_ = 0; q_ < 2; ++q_)
#pragma unroll
    for (int ks = 0; ks < 2; ++ks)
#pragma unroll
      for (int jj = 0; jj < 8; ++jj)
        qfr[q_][ks][jj] = (short)Qtp[base + (size_t)(ks * 32 + fq * 8 + jj) * S_LEN
                                    + (q0 + qg * 32 + q_ * 16 + fr)];

  float l_lane[2] = {0.f, 0.f};
  float4v o_acc[4][2] = {};                    // [df][q_], partial O^T over this k-half
  const float4v zero4 = {0.f, 0.f, 0.f, 0.f};

  // mask prefetch for tile 0 (bit k of ballot = mask[kv0+k] != 0)
  int mnext = mask[b * S_LEN + lane];

  // prologue: stage tile 0 into buffer 0
  stage_tile(smem, Kp, Vtp, base, 0, w, kr, kc);

#pragma unroll 2
  for (int it = 0; it < 32; ++it) {
    __syncthreads();   // drains vmcnt -> tile 'it' resident; buffer (it+1)&1 free
    if (it < 31)
      stage_tile(smem, Kp, Vtp, base, it + 1, w, kr, kc);   // in flight during compute

    unsigned long long bal = __ballot(mnext != 0);
    if (it < 31)
      mnext = mask[b * S_LEN + (it + 1) * 64 + lane];       // prefetch next tile's mask

    const unsigned short* sKb  = (const unsigned short*)(smem + (it & 1) * 16384);
    const unsigned short* sVtb = (const unsigned short*)(smem + (it & 1) * 16384 + 8192);

    // S^T = K · Q^T over this wave's 32-k strip (scores in log2 domain: Q pre-scaled)
    float4v s_acc[2][2];
#pragma unroll
    for (int kf = 0; kf < 2; ++kf) {
      int rk = kh * 32 + kf * 16 + fr;
      short8 k0 = *(const short8*)&sKb[rk * 64 + ((fq ^ (rk & 7)) * 8)];
      short8 k1 = *(const short8*)&sKb[rk * 64 + (((4 + fq) ^ (rk & 7)) * 8)];
#pragma unroll
      for (int q_ = 0; q_ < 2; ++q_) {
        float4v s = __builtin_amdgcn_mfma_f32_16x16x32_bf16(k0, qfr[q_][0], zero4, 0, 0, 0);
        s_acc[kf][q_] = __builtin_amdgcn_mfma_f32_16x16x32_bf16(k1, qfr[q_][1], s, 0, 0, 0);
      }
    }

    // V fragments early: LDS latency overlaps the softmax VALU below
    short8 vf[4];
#pragma unroll
    for (int df = 0; df < 4; ++df) {
      int rv = df * 16 + fr;
      vf[df] = *(const short8*)&sVtb[rv * 64 + (((kh * 4 + fq) ^ (fr & 7)) * 8)];
    }

    // exp2 -> (rare) mask zeroing -> pack P^T strip (cvt_pk) -> per-lane l partials
#pragma unroll
    for (int kf = 0; kf < 2; ++kf) {
      unsigned mseg = 0xFu;
      if (bal != ~0ull)                        // wave-uniform slow path
        mseg = (unsigned)(bal >> (kh * 32 + kf * 16 + fq * 4)) & 0xFu;
#pragma unroll
      for (int q_ = 0; q_ < 2; ++q_) {
        float p0 = __builtin_amdgcn_exp2f(s_acc[kf][q_][0]);
        float p1 = __builtin_amdgcn_exp2f(s_acc[kf][q_][1]);
        float p2 = __builtin_amdgcn_exp2f(s_acc[kf][q_][2]);
        float p3 = __builtin_amdgcn_exp2f(s_acc[kf][q_][3]);
        if (bal != ~0ull) {
          p0 = (mseg & 1u) ? p0 : 0.f;
          p1 = (mseg & 2u) ? p1 : 0.f;
          p2 = (mseg & 4u) ? p2 : 0.f;
          p3 = (mseg & 8u) ? p3 : 0.f;
        }
        l_lane[q_] += (p0 + p1) + (p2 + p3);
        uint2 pk;
        pk.x = cvtpk(p0, p1);
        pk.y = cvtpk(p2, p3);
        *(uint2*)&sPw[(q_ * 16 + fr) * 40 + (kf * 4 + fq) * 4] = pk;
      }
    }
    // no barrier: sP strip is per-wave; LDS ops are in-order within a wave

    // O^T += V^T · P^T over this wave's 32-k strip (single k-step)
    short8 pf[2];
#pragma unroll
    for (int q_ = 0; q_ < 2; ++q_)
      pf[q_] = *(const short8*)&sPw[(q_ * 16 + fr) * 40 + fq * 8];
#pragma unroll
    for (int df = 0; df < 4; ++df)
#pragma unroll
      for (int q_ = 0; q_ < 2; ++q_)
        o_acc[df][q_] = __builtin_amdgcn_mfma_f32_16x16x32_bf16(vf[df], pf[q_], o_acc[df][q_], 0, 0, 0);
  }

  // reduce l over fq within the wave
#pragma unroll
  for (int q_ = 0; q_ < 2; ++q_) {
    l_lane[q_] += __shfl_xor(l_lane[q_], 16);
    l_lane[q_] += __shfl_xor(l_lane[q_], 32);
  }

  // cross-wave-pair (kh) reduction via LDS.
  // Record: 32 O floats + 2 l floats, stride 34 (136 B). 4 pairs x 64 lanes x 136 B
  // = 34816 B, aliasing the dbuf + wave-0's P strip (all dead after the barrier).
  __syncthreads();   // all waves done with buffers/strips before aliasing
  float* red = (float*)smem;
  float* rec = red + (size_t)(qg * 64 + lane) * 34;
  if (kh) {
#pragma unroll
    for (int df = 0; df < 4; ++df)
#pragma unroll
      for (int q_ = 0; q_ < 2; ++q_) {
        int e = df * 2 + q_;
        *(float2*)&rec[4 * e]     = make_float2(o_acc[df][q_][0], o_acc[df][q_][1]);
        *(float2*)&rec[4 * e + 2] = make_float2(o_acc[df][q_][2], o_acc[df][q_][3]);
      }
    *(float2*)&rec[32] = make_float2(l_lane[0], l_lane[1]);
  }
  __syncthreads();
  if (!kh) {
#pragma unroll
    for (int df = 0; df < 4; ++df)
#pragma unroll
      for (int q_ = 0; q_ < 2; ++q_) {
        int e = df * 2 + q_;
        float2 a = *(float2*)&rec[4 * e];
        float2 c = *(float2*)&rec[4 * e + 2];
        o_acc[df][q_][0] += a.x; o_acc[df][q_][1] += a.y;
        o_acc[df][q_][2] += c.x; o_acc[df][q_][3] += c.y;
      }
    float2 lr = *(float2*)&rec[32];
    float inv_l[2];
    inv_l[0] = 1.0f / (l_lane[0] + lr.x);
    inv_l[1] = 1.0f / (l_lane[1] + lr.y);
    // epilogue: O^T C-layout -> 4 consecutive d per lane -> packed 8B stores
#pragma unroll
    for (int q_ = 0; q_ < 2; ++q_) {
      size_t rowoff = ((size_t)(b * S_LEN + q0 + qg * 32 + q_ * 16 + fr)) * HDIM + h * HD;
#pragma unroll
      for (int df = 0; df < 4; ++df) {
        uint2 pk;
        pk.x = pkbf(o_acc[df][q_][0] * inv_l[q_], o_acc[df][q_][1] * inv_l[q_]);
        pk.y = pkbf(o_acc[df][q_][2] * inv_l[q_], o_acc[df][q_][3] * inv_l[q_]);
        *(uint2*)&ctx[rowoff + df * 16 + fq * 4] = pk;
      }
    }
  }
}

extern "C" void kernel_launch(void* const* d_in, const int* in_sizes, int n_in,
                              void* d_out, int out_size, void* d_ws, size_t ws_size,
                              hipStream_t stream) {
  const float* X  = (const float*)d_in[0];
  const int* mask = (const int*)d_in[1];
  const float* Wq = (const float*)d_in[2];
  const float* Wk = (const float*)d_in[3];
  const float* Wv = (const float*)d_in[4];
  const float* Wo = (const float*)d_in[5];
  float* out = (float*)d_out;

  char* ws = (char*)d_ws;
  // layout (40 MB): [0,8M) Xb then reused as CTX; [8M,16M) Wt x4; [16M,40M) Q^T,K,V^T bf16
  unsigned short* Xb  = (unsigned short*)(ws);
  unsigned short* Wt  = (unsigned short*)(ws + (8u << 20));
  unsigned short* QKV = (unsigned short*)(ws + (16u << 20));
  unsigned short* CTX = (unsigned short*)(ws);   // reuse Xb region (dead after QKV GEMM)

  prep_kernel<<<5120, 256, 0, stream>>>(X, Xb, Wq, Wk, Wv, Wo, Wt);
  gemm_qkv_kernel<<<dim3(32, 16), 256, 0, stream>>>(Xb, Wt, QKV);
  attn_kernel<<<dim3(16, 32), 512, 0, stream>>>(
      QKV, QKV + QKV_STRIDE, QKV + 2 * (size_t)QKV_STRIDE, mask, CTX);
  gemm128_kernel<<<dim3(32, 8), 256, 0, stream>>>(CTX, Wt + (3u << 20), out);
}

// Round 12
// 181.495 us; speedup vs baseline: 1.2017x; 1.0247x over previous
//
#include <hip/hip_runtime.h>
#include <hip/hip_bf16.h>

#define S_LEN 2048
#define HDIM  1024
#define NHEADS 16
#define HD    64
#define QKV_STRIDE (S_LEN * 2 * HDIM)   // 4194304 elements per tensor

typedef __attribute__((ext_vector_type(8))) short short8;
typedef __attribute__((ext_vector_type(4))) float float4v;

// cheap bf16 convert: round-half-up (bias ~2^-24 rel, negligible vs bf16 eps)
__device__ __forceinline__ unsigned short f2bf(float f) {
  return (unsigned short)((__builtin_bit_cast(unsigned int, f) + 0x8000u) >> 16);
}
// pack two floats -> two bf16 in one u32 via v_perm_b32 (3 VALU ops)
__device__ __forceinline__ unsigned int pkbf(float a, float b) {
  unsigned int ua = __builtin_bit_cast(unsigned int, a) + 0x8000u;
  unsigned int ub = __builtin_bit_cast(unsigned int, b) + 0x8000u;
  return __builtin_amdgcn_perm(ub, ua, 0x07060302u);  // {ub.hi16, ua.hi16}
}
// pack two floats -> two bf16 in ONE VALU op (RNE). Numerics proven in R1/R9/R11.
__device__ __forceinline__ unsigned int cvtpk(float a, float b) {
  unsigned int r;
  asm("v_cvt_pk_bf16_f32 %0, %1, %2" : "=v"(r) : "v"(a), "v"(b));
  return r;
}

__device__ __forceinline__ void async_copy16(const void* g, void* l) {
  __builtin_amdgcn_global_load_lds((__attribute__((address_space(1))) const void*)g,
                                   (__attribute__((address_space(3))) void*)l, 16, 0, 0);
}

// ---------------- fused prep: cast X (fp32->bf16) + transpose/cast weights ----------------
// blocks [0,4096): X cast, 4 elems/thread. blocks [4096,5120): W transpose tiles.
__global__ void prep_kernel(const float* __restrict__ X, unsigned short* __restrict__ Xb,
                            const float* __restrict__ W0, const float* __restrict__ W1,
                            const float* __restrict__ W2, const float* __restrict__ W3,
                            unsigned short* __restrict__ Wt) {
  __shared__ unsigned short tile[64][72];   // [n_loc][k_loc], padded (trans branch only)
  const int t = threadIdx.x;
  if (blockIdx.x < 4096) {
    int i = blockIdx.x * 256 + t;          // 0 .. 1048575 float4 chunks
    float4 v = ((const float4*)X)[i];
    uint2 o;
    o.x = pkbf(v.x, v.y);
    o.y = pkbf(v.z, v.w);
    ((uint2*)Xb)[i] = o;
    return;
  }
  const int wid = blockIdx.x - 4096;       // 0..1023
  const int z = wid >> 8;                  // 0..3
  const int rem = wid & 255;
  const int n0 = (rem & 15) * 64;
  const int k0 = (rem >> 4) * 64;
  const float* W = (z == 0) ? W0 : (z == 1) ? W1 : (z == 2) ? W2 : W3;
  unsigned short* out = Wt + (size_t)z * HDIM * HDIM;
#pragma unroll
  for (int it = 0; it < 4; ++it) {
    int idx = it * 256 + t;          // 1024 float4 chunks
    int r  = idx >> 4;               // k_loc 0..63
    int c4 = (idx & 15) * 4;         // n_loc
    float4 v = *(const float4*)&W[(size_t)(k0 + r) * HDIM + n0 + c4];
    tile[c4 + 0][r] = f2bf(v.x);
    tile[c4 + 1][r] = f2bf(v.y);
    tile[c4 + 2][r] = f2bf(v.z);
    tile[c4 + 3][r] = f2bf(v.w);
  }
  __syncthreads();
#pragma unroll
  for (int it = 0; it < 4; ++it) {
    int idx = it * 256 + t;
    int r  = idx >> 4;               // n_loc
    int c4 = (idx & 15) * 4;         // k_loc
    ushort4 o;
    o.x = tile[r][c4 + 0]; o.y = tile[r][c4 + 1];
    o.z = tile[r][c4 + 2]; o.w = tile[r][c4 + 3];
    *(ushort4*)&out[(size_t)(n0 + r) * HDIM + k0 + c4] = o;
  }
}

// ---------------- fused QKV GEMM, 128x64 tile, DOUBLE-BUFFERED (frozen at R11) ----------------
// stage(ks+1) into the other buffer AFTER the barrier, compute buf ks&1; copies drain
// at the NEXT barrier, a full compute phase later.
__global__ __launch_bounds__(256, 2) void gemm_qkv_kernel(
    const unsigned short* __restrict__ A,
    const unsigned short* __restrict__ Wt,   // 3 B^T matrices, 1M elements apart
    unsigned short* __restrict__ out)
{
  __shared__ unsigned short sA[2 * 128 * 32];      // 16 KB
  __shared__ unsigned short sB[2 * 3 * 64 * 32];   // 24 KB
  const int m0 = blockIdx.x * 128;
  const int n0 = blockIdx.y * 64;
  const int t = threadIdx.x;
  const int lane = t & 63;
  const int w = t >> 6;
  const int wm = w & 1, wn = w >> 1;

  const int sr  = lane >> 2;                  // row within 16
  const int scp = lane & 3;                   // physical chunk
  const int scl = scp ^ ((sr >> 1) & 3);      // logical (global) k-chunk
  const long ga0 = (long)(m0 + 16 * w + sr) * HDIM + scl * 8;
  const long ga1 = ga0 + 64l * HDIM;
  const long gb  = (long)(n0 + 16 * w + sr) * HDIM + scl * 8;

  const int fr = lane & 15;
  const int fq = lane >> 4;
  int offA[4], offB[2];
#pragma unroll
  for (int i = 0; i < 4; ++i) {
    int ra = wm * 64 + i * 16 + fr;
    offA[i] = ra * 32 + (fq ^ ((ra >> 1) & 3)) * 8;
  }
#pragma unroll
  for (int i = 0; i < 2; ++i) {
    int rb = wn * 32 + i * 16 + fr;
    offB[i] = rb * 32 + (fq ^ ((rb >> 1) & 3)) * 8;
  }

  float4v acc[3][4][2] = {};

  // stage K-step ks into buffer ks&1 (5 copies per wave)
  auto stage = [&](int ks) {
    const int kk = ks * 32;
    unsigned short* A0 = &sA[(ks & 1) * 4096 + (16 * w) * 32];
    unsigned short* Bb = &sB[(ks & 1) * 6144 + (16 * w) * 32];
    async_copy16(A + ga0 + kk, A0);
    async_copy16(A + ga1 + kk, A0 + 2048);
#pragma unroll
    for (int z = 0; z < 3; ++z)
      async_copy16(Wt + (long)z * (HDIM * HDIM) + gb + kk, Bb + z * 2048);
  };

  stage(0);
#pragma unroll 2
  for (int ks = 0; ks < 32; ++ks) {
    __syncthreads();                 // vmcnt drain -> tile ks resident
    if (ks < 31) stage(ks + 1);      // in flight during compute below
    const unsigned short* a  = &sA[(ks & 1) * 4096];
    const unsigned short* bb = &sB[(ks & 1) * 6144];
    short8 af[4];
#pragma unroll
    for (int i = 0; i < 4; ++i) af[i] = *(const short8*)&a[offA[i]];
#pragma unroll
    for (int z = 0; z < 3; ++z) {
      short8 b0 = *(const short8*)&bb[z * 2048 + offB[0]];
      short8 b1 = *(const short8*)&bb[z * 2048 + offB[1]];
#pragma unroll
      for (int mi = 0; mi < 4; ++mi) {
        acc[z][mi][0] = __builtin_amdgcn_mfma_f32_16x16x32_bf16(af[mi], b0, acc[z][mi][0], 0, 0, 0);
        acc[z][mi][1] = __builtin_amdgcn_mfma_f32_16x16x32_bf16(af[mi], b1, acc[z][mi][1], 0, 0, 0);
      }
    }
  }

  // ---- epilogues ----
  // z==0 (Q^T, scaled) and z==2 (V^T): packed (b,h,d,s)
#pragma unroll
  for (int z = 0; z < 3; z += 2) {
    const float scle = (z == 0) ? 0.18033688011112042f : 1.0f;
    unsigned short* o = out + (size_t)z * QKV_STRIDE;
#pragma unroll
    for (int mi = 0; mi < 4; ++mi)
#pragma unroll
      for (int ni = 0; ni < 2; ++ni) {
        int m = m0 + wm * 64 + mi * 16 + fq * 4;   // s base (multiple of 4)
        int n = n0 + wn * 32 + ni * 16 + fr;
        int b = m >> 11, s = m & 2047, hh = n >> 6, d = n & 63;
        uint2 pk;
        pk.x = pkbf(acc[z][mi][ni][0] * scle, acc[z][mi][ni][1] * scle);
        pk.y = pkbf(acc[z][mi][ni][2] * scle, acc[z][mi][ni][3] * scle);
        *(uint2*)&o[(((size_t)(b * NHEADS + hh)) * HD + d) * S_LEN + s] = pk;
      }
  }
  // z==1 (K): natural (b,h,s,d) scatter
  {
    unsigned short* o = out + (size_t)QKV_STRIDE;
#pragma unroll
    for (int mi = 0; mi < 4; ++mi)
#pragma unroll
      for (int ni = 0; ni < 2; ++ni)
#pragma unroll
        for (int rg = 0; rg < 4; ++rg) {
          int m = m0 + wm * 64 + mi * 16 + fq * 4 + rg;
          int n = n0 + wn * 32 + ni * 16 + fr;
          int b = m >> 11, s = m & 2047, hh = n >> 6, d = n & 63;
          o[(((size_t)(b * NHEADS + hh)) * S_LEN + s) * HD + d] = f2bf(acc[1][mi][ni][rg]);
        }
  }
}

// ------------- O-projection GEMM, 128x64 tile, dbuf, 2 blocks/CU (R12) -------------
// R12: tile 128x128 -> 128x64. Grid was 256 = exactly 1 block/CU -- the worst TLP in
// the pipeline: the barrier-locked K-loop had ZERO co-resident peers to hide staging
// latency. Now grid 512 = 2/CU. Cost: A-panel L2 re-reads double (+~64MB L2 ~ +2us);
// per-wave MFMA per K-step halves 16->8. LDS dbuf 2x(8+4) = 24 KB.
// R9's 64x64-both-GEMMs test conflated QKV + O-proj; this isolates O-proj.
__global__ __launch_bounds__(256, 3) void gemm128_kernel(
    const unsigned short* __restrict__ A,
    const unsigned short* __restrict__ Bt,
    float* __restrict__ out)
{
  __shared__ unsigned short sA[2 * 128 * 32];   // 16 KB
  __shared__ unsigned short sB[2 * 64 * 32];    // 8 KB
  const int m0 = blockIdx.x * 128;
  const int n0 = blockIdx.y * 64;
  const int t = threadIdx.x;
  const int lane = t & 63;
  const int w = t >> 6;
  const int wm = w & 1, wn = w >> 1;

  const int sr  = lane >> 2;                  // row within 16
  const int scp = lane & 3;                   // physical chunk
  const int scl = scp ^ ((sr >> 1) & 3);      // logical (global) k-chunk
  const long ga0 = (long)(m0 + 16 * w + sr) * HDIM + scl * 8;
  const long ga1 = ga0 + 64l * HDIM;
  const long gb0 = (long)(n0 + 16 * w + sr) * HDIM + scl * 8;

  const int fr = lane & 15;
  const int fq = lane >> 4;
  int offA[4], offB[2];
#pragma unroll
  for (int i = 0; i < 4; ++i) {
    int ra = wm * 64 + i * 16 + fr;
    offA[i] = ra * 32 + (fq ^ ((ra >> 1) & 3)) * 8;
  }
#pragma unroll
  for (int i = 0; i < 2; ++i) {
    int rb = wn * 32 + i * 16 + fr;
    offB[i] = rb * 32 + (fq ^ ((rb >> 1) & 3)) * 8;
  }

  float4v acc[4][2] = {};

  auto stage = [&](int ks) {
    const int kk = ks * 32;
    unsigned short* A0 = &sA[(ks & 1) * 4096 + (16 * w) * 32];
    unsigned short* B0 = &sB[(ks & 1) * 2048 + (16 * w) * 32];
    async_copy16(A + ga0 + kk, A0);
    async_copy16(A + ga1 + kk, A0 + 2048);
    async_copy16(Bt + gb0 + kk, B0);
  };

  stage(0);
#pragma unroll 2
  for (int ks = 0; ks < 32; ++ks) {
    __syncthreads();                 // vmcnt drain -> tile ks resident
    if (ks < 31) stage(ks + 1);      // overlapped with compute below
    const unsigned short* a = &sA[(ks & 1) * 4096];
    const unsigned short* bp = &sB[(ks & 1) * 2048];
    short8 af[4], bf[2];
#pragma unroll
    for (int i = 0; i < 4; ++i) af[i] = *(const short8*)&a[offA[i]];
#pragma unroll
    for (int i = 0; i < 2; ++i) bf[i] = *(const short8*)&bp[offB[i]];
#pragma unroll
    for (int mi = 0; mi < 4; ++mi)
#pragma unroll
      for (int ni = 0; ni < 2; ++ni)
        acc[mi][ni] = __builtin_amdgcn_mfma_f32_16x16x32_bf16(af[mi], bf[ni], acc[mi][ni], 0, 0, 0);
  }

#pragma unroll
  for (int mi = 0; mi < 4; ++mi)
#pragma unroll
    for (int ni = 0; ni < 2; ++ni)
#pragma unroll
      for (int rg = 0; rg < 4; ++rg) {
        int m = m0 + wm * 64 + mi * 16 + fq * 4 + rg;
        int n = n0 + wn * 32 + ni * 16 + fr;
        out[(size_t)m * HDIM + n] = acc[mi][ni][rg];
      }
}

// stage one 64-k tile (K 8 KB + V^T 8 KB) into buffer (tile&1); 2 DMA copies per wave
__device__ __forceinline__ void stage_tile(char* smem, const unsigned short* Kp,
    const unsigned short* Vtp, size_t base, int tile, int w, int kr, int kc) {
  const int kv = tile * 64;
  char* bufb = smem + (tile & 1) * 16384;
  unsigned short* dK = (unsigned short*)bufb + (w * 8) * 64;
  async_copy16(Kp + base + (size_t)(kv + w * 8 + kr) * HD + ((kc ^ kr) * 8), dK);
  unsigned short* dV = (unsigned short*)(bufb + 8192) + (w * 8) * 64;
  const int d = w * 8 + kr;
  async_copy16(Vtp + base + (size_t)d * S_LEN + kv + ((kc ^ kr) * 8), dV);
}

// ---------------- flash attention: split-k waves, fixed-base softmax, ----------------
// ---------------- BN=64 double-buffered staging, ONE barrier per tile ----------------
// Frozen at R11 (best verified: 52.5us, absmax 2.75e-4): XCD remap (FETCH 70->12.4MB)
// + cvt_pk P-pack (-4us, R9). setprio/PV-pipelining dropped (null); q-split reverted
// (R10 numerics failure, cause unidentified after two audits).
__global__ __launch_bounds__(512, 4) void attn_kernel(
    const unsigned short* __restrict__ Qtp,
    const unsigned short* __restrict__ Kp,
    const unsigned short* __restrict__ Vtp,
    const int* __restrict__ mask,
    unsigned short* __restrict__ ctx)
{
  __shared__ __align__(16) char smem[53248];

  // XCD-aware remap: p in [0,512); bh = (p&7)+8*(j>>4), q-tile = j&15, j = p>>3.
  // Bijective: p = (bh&7) + 8*((bh>>3)*16 + qt).
  const int p = blockIdx.x + 16 * blockIdx.y;
  const int j = p >> 3;
  const int bh = (p & 7) + 8 * (j >> 4);
  const int q0 = (j & 15) * 128;

  const int b = bh >> 4;
  const int h = bh & 15;
  const size_t base = (size_t)bh * (S_LEN * HD);
  const int t = threadIdx.x;
  const int lane = t & 63;
  const int w = t >> 6;                        // 0..7
  const int qg = w >> 1;                       // q-group (32 q)
  const int kh = w & 1;                        // k-half (32 k)
  const int fr = lane & 15;
  const int fq = lane >> 4;
  const int kr = lane >> 3, kc = lane & 7;     // staging lane map
  unsigned short* sPw = (unsigned short*)(smem + 32768) + w * (32 * 40);

  // Q fragments (B-operand): 32 q rows, from transposed (b,h,d,s) layout
  short8 qfr[2][2];
#pragma unroll
  for (int q_ = 0; q_ < 2; ++q_)
#pragma unroll
    for (int ks = 0; ks < 2; ++ks)
#pragma unroll
      for (int jj = 0; jj < 8; ++jj)
        qfr[q_][ks][jj] = (short)Qtp[base + (size_t)(ks * 32 + fq * 8 + jj) * S_LEN
                                    + (q0 + qg * 32 + q_ * 16 + fr)];

  float l_lane[2] = {0.f, 0.f};
  float4v o_acc[4][2] = {};                    // [df][q_], partial O^T over this k-half
  const float4v zero4 = {0.f, 0.f, 0.f, 0.f};

  // mask prefetch for tile 0 (bit k of ballot = mask[kv0+k] != 0)
  int mnext = mask[b * S_LEN + lane];

  // prologue: stage tile 0 into buffer 0
  stage_tile(smem, Kp, Vtp, base, 0, w, kr, kc);

#pragma unroll 2
  for (int it = 0; it < 32; ++it) {
    __syncthreads();   // drains vmcnt -> tile 'it' resident; buffer (it+1)&1 free
    if (it < 31)
      stage_tile(smem, Kp, Vtp, base, it + 1, w, kr, kc);   // in flight during compute

    unsigned long long bal = __ballot(mnext != 0);
    if (it < 31)
      mnext = mask[b * S_LEN + (it + 1) * 64 + lane];       // prefetch next tile's mask

    const unsigned short* sKb  = (const unsigned short*)(smem + (it & 1) * 16384);
    const unsigned short* sVtb = (const unsigned short*)(smem + (it & 1) * 16384 + 8192);

    // S^T = K · Q^T over this wave's 32-k strip (scores in log2 domain: Q pre-scaled)
    float4v s_acc[2][2];
#pragma unroll
    for (int kf = 0; kf < 2; ++kf) {
      int rk = kh * 32 + kf * 16 + fr;
      short8 k0 = *(const short8*)&sKb[rk * 64 + ((fq ^ (rk & 7)) * 8)];
      short8 k1 = *(const short8*)&sKb[rk * 64 + (((4 + fq) ^ (rk & 7)) * 8)];
#pragma unroll
      for (int q_ = 0; q_ < 2; ++q_) {
        float4v s = __builtin_amdgcn_mfma_f32_16x16x32_bf16(k0, qfr[q_][0], zero4, 0, 0, 0);
        s_acc[kf][q_] = __builtin_amdgcn_mfma_f32_16x16x32_bf16(k1, qfr[q_][1], s, 0, 0, 0);
      }
    }

    // V fragments early: LDS latency overlaps the softmax VALU below
    short8 vf[4];
#pragma unroll
    for (int df = 0; df < 4; ++df) {
      int rv = df * 16 + fr;
      vf[df] = *(const short8*)&sVtb[rv * 64 + (((kh * 4 + fq) ^ (fr & 7)) * 8)];
    }

    // exp2 -> (rare) mask zeroing -> pack P^T strip (cvt_pk) -> per-lane l partials
#pragma unroll
    for (int kf = 0; kf < 2; ++kf) {
      unsigned mseg = 0xFu;
      if (bal != ~0ull)                        // wave-uniform slow path
        mseg = (unsigned)(bal >> (kh * 32 + kf * 16 + fq * 4)) & 0xFu;
#pragma unroll
      for (int q_ = 0; q_ < 2; ++q_) {
        float p0 = __builtin_amdgcn_exp2f(s_acc[kf][q_][0]);
        float p1 = __builtin_amdgcn_exp2f(s_acc[kf][q_][1]);
        float p2 = __builtin_amdgcn_exp2f(s_acc[kf][q_][2]);
        float p3 = __builtin_amdgcn_exp2f(s_acc[kf][q_][3]);
        if (bal != ~0ull) {
          p0 = (mseg & 1u) ? p0 : 0.f;
          p1 = (mseg & 2u) ? p1 : 0.f;
          p2 = (mseg & 4u) ? p2 : 0.f;
          p3 = (mseg & 8u) ? p3 : 0.f;
        }
        l_lane[q_] += (p0 + p1) + (p2 + p3);
        uint2 pk;
        pk.x = cvtpk(p0, p1);
        pk.y = cvtpk(p2, p3);
        *(uint2*)&sPw[(q_ * 16 + fr) * 40 + (kf * 4 + fq) * 4] = pk;
      }
    }
    // no barrier: sP strip is per-wave; LDS ops are in-order within a wave

    // O^T += V^T · P^T over this wave's 32-k strip (single k-step)
    short8 pf[2];
#pragma unroll
    for (int q_ = 0; q_ < 2; ++q_)
      pf[q_] = *(const short8*)&sPw[(q_ * 16 + fr) * 40 + fq * 8];
#pragma unroll
    for (int df = 0; df < 4; ++df)
#pragma unroll
      for (int q_ = 0; q_ < 2; ++q_)
        o_acc[df][q_] = __builtin_amdgcn_mfma_f32_16x16x32_bf16(vf[df], pf[q_], o_acc[df][q_], 0, 0, 0);
  }

  // reduce l over fq within the wave
#pragma unroll
  for (int q_ = 0; q_ < 2; ++q_) {
    l_lane[q_] += __shfl_xor(l_lane[q_], 16);
    l_lane[q_] += __shfl_xor(l_lane[q_], 32);
  }

  // cross-wave-pair (kh) reduction via LDS.
  // Record: 32 O floats + 2 l floats, stride 34 (136 B). 4 pairs x 64 lanes x 136 B
  // = 34816 B, aliasing the dbuf + wave-0's P strip (all dead after the barrier).
  __syncthreads();   // all waves done with buffers/strips before aliasing
  float* red = (float*)smem;
  float* rec = red + (size_t)(qg * 64 + lane) * 34;
  if (kh) {
#pragma unroll
    for (int df = 0; df < 4; ++df)
#pragma unroll
      for (int q_ = 0; q_ < 2; ++q_) {
        int e = df * 2 + q_;
        *(float2*)&rec[4 * e]     = make_float2(o_acc[df][q_][0], o_acc[df][q_][1]);
        *(float2*)&rec[4 * e + 2] = make_float2(o_acc[df][q_][2], o_acc[df][q_][3]);
      }
    *(float2*)&rec[32] = make_float2(l_lane[0], l_lane[1]);
  }
  __syncthreads();
  if (!kh) {
#pragma unroll
    for (int df = 0; df < 4; ++df)
#pragma unroll
      for (int q_ = 0; q_ < 2; ++q_) {
        int e = df * 2 + q_;
        float2 a = *(float2*)&rec[4 * e];
        float2 c = *(float2*)&rec[4 * e + 2];
        o_acc[df][q_][0] += a.x; o_acc[df][q_][1] += a.y;
        o_acc[df][q_][2] += c.x; o_acc[df][q_][3] += c.y;
      }
    float2 lr = *(float2*)&rec[32];
    float inv_l[2];
    inv_l[0] = 1.0f / (l_lane[0] + lr.x);
    inv_l[1] = 1.0f / (l_lane[1] + lr.y);
    // epilogue: O^T C-layout -> 4 consecutive d per lane -> packed 8B stores
#pragma unroll
    for (int q_ = 0; q_ < 2; ++q_) {
      size_t rowoff = ((size_t)(b * S_LEN + q0 + qg * 32 + q_ * 16 + fr)) * HDIM + h * HD;
#pragma unroll
      for (int df = 0; df < 4; ++df) {
        uint2 pk;
        pk.x = pkbf(o_acc[df][q_][0] * inv_l[q_], o_acc[df][q_][1] * inv_l[q_]);
        pk.y = pkbf(o_acc[df][q_][2] * inv_l[q_], o_acc[df][q_][3] * inv_l[q_]);
        *(uint2*)&ctx[rowoff + df * 16 + fq * 4] = pk;
      }
    }
  }
}

extern "C" void kernel_launch(void* const* d_in, const int* in_sizes, int n_in,
                              void* d_out, int out_size, void* d_ws, size_t ws_size,
                              hipStream_t stream) {
  const float* X  = (const float*)d_in[0];
  const int* mask = (const int*)d_in[1];
  const float* Wq = (const float*)d_in[2];
  const float* Wk = (const float*)d_in[3];
  const float* Wv = (const float*)d_in[4];
  const float* Wo = (const float*)d_in[5];
  float* out = (float*)d_out;

  char* ws = (char*)d_ws;
  // layout (40 MB): [0,8M) Xb then reused as CTX; [8M,16M) Wt x4; [16M,40M) Q^T,K,V^T bf16
  unsigned short* Xb  = (unsigned short*)(ws);
  unsigned short* Wt  = (unsigned short*)(ws + (8u << 20));
  unsigned short* QKV = (unsigned short*)(ws + (16u << 20));
  unsigned short* CTX = (unsigned short*)(ws);   // reuse Xb region (dead after QKV GEMM)

  prep_kernel<<<5120, 256, 0, stream>>>(X, Xb, Wq, Wk, Wv, Wo, Wt);
  gemm_qkv_kernel<<<dim3(32, 16), 256, 0, stream>>>(Xb, Wt, QKV);
  attn_kernel<<<dim3(16, 32), 512, 0, stream>>>(
      QKV, QKV + QKV_STRIDE, QKV + 2 * (size_t)QKV_STRIDE, mask, CTX);
  gemm128_kernel<<<dim3(32, 16), 256, 0, stream>>>(CTX, Wt + (3u << 20), out);
}

// Round 13
// 180.136 us; speedup vs baseline: 1.2108x; 1.0075x over previous
//
#include <hip/hip_runtime.h>
#include <hip/hip_bf16.h>

#define S_LEN 2048
#define HDIM  1024
#define NHEADS 16
#define HD    64
#define QKV_STRIDE (S_LEN * 2 * HDIM)   // 4194304 elements per tensor

typedef __attribute__((ext_vector_type(8))) short short8;
typedef __attribute__((ext_vector_type(4))) float float4v;

// cheap bf16 convert: round-half-up (bias ~2^-24 rel, negligible vs bf16 eps)
__device__ __forceinline__ unsigned short f2bf(float f) {
  return (unsigned short)((__builtin_bit_cast(unsigned int, f) + 0x8000u) >> 16);
}
// pack two floats -> two bf16 in one u32 via v_perm_b32 (3 VALU ops)
__device__ __forceinline__ unsigned int pkbf(float a, float b) {
  unsigned int ua = __builtin_bit_cast(unsigned int, a) + 0x8000u;
  unsigned int ub = __builtin_bit_cast(unsigned int, b) + 0x8000u;
  return __builtin_amdgcn_perm(ub, ua, 0x07060302u);  // {ub.hi16, ua.hi16}
}
// pack two floats -> two bf16 in ONE VALU op (RNE). Numerics proven in R1/R9/R11.
__device__ __forceinline__ unsigned int cvtpk(float a, float b) {
  unsigned int r;
  asm("v_cvt_pk_bf16_f32 %0, %1, %2" : "=v"(r) : "v"(a), "v"(b));
  return r;
}

__device__ __forceinline__ void async_copy16(const void* g, void* l) {
  __builtin_amdgcn_global_load_lds((__attribute__((address_space(1))) const void*)g,
                                   (__attribute__((address_space(3))) void*)l, 16, 0, 0);
}

// ---------------- fused prep: cast X (fp32->bf16) + transpose/cast weights ----------------
// blocks [0,4096): X cast, 4 elems/thread. blocks [4096,5120): W transpose tiles.
__global__ void prep_kernel(const float* __restrict__ X, unsigned short* __restrict__ Xb,
                            const float* __restrict__ W0, const float* __restrict__ W1,
                            const float* __restrict__ W2, const float* __restrict__ W3,
                            unsigned short* __restrict__ Wt) {
  __shared__ unsigned short tile[64][72];   // [n_loc][k_loc], padded (trans branch only)
  const int t = threadIdx.x;
  if (blockIdx.x < 4096) {
    int i = blockIdx.x * 256 + t;          // 0 .. 1048575 float4 chunks
    float4 v = ((const float4*)X)[i];
    uint2 o;
    o.x = pkbf(v.x, v.y);
    o.y = pkbf(v.z, v.w);
    ((uint2*)Xb)[i] = o;
    return;
  }
  const int wid = blockIdx.x - 4096;       // 0..1023
  const int z = wid >> 8;                  // 0..3
  const int rem = wid & 255;
  const int n0 = (rem & 15) * 64;
  const int k0 = (rem >> 4) * 64;
  const float* W = (z == 0) ? W0 : (z == 1) ? W1 : (z == 2) ? W2 : W3;
  unsigned short* out = Wt + (size_t)z * HDIM * HDIM;
#pragma unroll
  for (int it = 0; it < 4; ++it) {
    int idx = it * 256 + t;          // 1024 float4 chunks
    int r  = idx >> 4;               // k_loc 0..63
    int c4 = (idx & 15) * 4;         // n_loc
    float4 v = *(const float4*)&W[(size_t)(k0 + r) * HDIM + n0 + c4];
    tile[c4 + 0][r] = f2bf(v.x);
    tile[c4 + 1][r] = f2bf(v.y);
    tile[c4 + 2][r] = f2bf(v.z);
    tile[c4 + 3][r] = f2bf(v.w);
  }
  __syncthreads();
#pragma unroll
  for (int it = 0; it < 4; ++it) {
    int idx = it * 256 + t;
    int r  = idx >> 4;               // n_loc
    int c4 = (idx & 15) * 4;         // k_loc
    ushort4 o;
    o.x = tile[r][c4 + 0]; o.y = tile[r][c4 + 1];
    o.z = tile[r][c4 + 2]; o.w = tile[r][c4 + 3];
    *(ushort4*)&out[(size_t)(n0 + r) * HDIM + k0 + c4] = o;
  }
}

// ---------------- fused QKV GEMM, 128x64 tile, DOUBLE-BUFFERED (frozen at R11) ----------------
__global__ __launch_bounds__(256, 2) void gemm_qkv_kernel(
    const unsigned short* __restrict__ A,
    const unsigned short* __restrict__ Wt,   // 3 B^T matrices, 1M elements apart
    unsigned short* __restrict__ out)
{
  __shared__ unsigned short sA[2 * 128 * 32];      // 16 KB
  __shared__ unsigned short sB[2 * 3 * 64 * 32];   // 24 KB
  const int m0 = blockIdx.x * 128;
  const int n0 = blockIdx.y * 64;
  const int t = threadIdx.x;
  const int lane = t & 63;
  const int w = t >> 6;
  const int wm = w & 1, wn = w >> 1;

  const int sr  = lane >> 2;                  // row within 16
  const int scp = lane & 3;                   // physical chunk
  const int scl = scp ^ ((sr >> 1) & 3);      // logical (global) k-chunk
  const long ga0 = (long)(m0 + 16 * w + sr) * HDIM + scl * 8;
  const long ga1 = ga0 + 64l * HDIM;
  const long gb  = (long)(n0 + 16 * w + sr) * HDIM + scl * 8;

  const int fr = lane & 15;
  const int fq = lane >> 4;
  int offA[4], offB[2];
#pragma unroll
  for (int i = 0; i < 4; ++i) {
    int ra = wm * 64 + i * 16 + fr;
    offA[i] = ra * 32 + (fq ^ ((ra >> 1) & 3)) * 8;
  }
#pragma unroll
  for (int i = 0; i < 2; ++i) {
    int rb = wn * 32 + i * 16 + fr;
    offB[i] = rb * 32 + (fq ^ ((rb >> 1) & 3)) * 8;
  }

  float4v acc[3][4][2] = {};

  // stage K-step ks into buffer ks&1 (5 copies per wave)
  auto stage = [&](int ks) {
    const int kk = ks * 32;
    unsigned short* A0 = &sA[(ks & 1) * 4096 + (16 * w) * 32];
    unsigned short* Bb = &sB[(ks & 1) * 6144 + (16 * w) * 32];
    async_copy16(A + ga0 + kk, A0);
    async_copy16(A + ga1 + kk, A0 + 2048);
#pragma unroll
    for (int z = 0; z < 3; ++z)
      async_copy16(Wt + (long)z * (HDIM * HDIM) + gb + kk, Bb + z * 2048);
  };

  stage(0);
#pragma unroll 2
  for (int ks = 0; ks < 32; ++ks) {
    __syncthreads();                 // vmcnt drain -> tile ks resident
    if (ks < 31) stage(ks + 1);      // in flight during compute below
    const unsigned short* a  = &sA[(ks & 1) * 4096];
    const unsigned short* bb = &sB[(ks & 1) * 6144];
    short8 af[4];
#pragma unroll
    for (int i = 0; i < 4; ++i) af[i] = *(const short8*)&a[offA[i]];
#pragma unroll
    for (int z = 0; z < 3; ++z) {
      short8 b0 = *(const short8*)&bb[z * 2048 + offB[0]];
      short8 b1 = *(const short8*)&bb[z * 2048 + offB[1]];
#pragma unroll
      for (int mi = 0; mi < 4; ++mi) {
        acc[z][mi][0] = __builtin_amdgcn_mfma_f32_16x16x32_bf16(af[mi], b0, acc[z][mi][0], 0, 0, 0);
        acc[z][mi][1] = __builtin_amdgcn_mfma_f32_16x16x32_bf16(af[mi], b1, acc[z][mi][1], 0, 0, 0);
      }
    }
  }

  // ---- epilogues ----
  // z==0 (Q^T, scaled) and z==2 (V^T): packed (b,h,d,s)
#pragma unroll
  for (int z = 0; z < 3; z += 2) {
    const float scle = (z == 0) ? 0.18033688011112042f : 1.0f;
    unsigned short* o = out + (size_t)z * QKV_STRIDE;
#pragma unroll
    for (int mi = 0; mi < 4; ++mi)
#pragma unroll
      for (int ni = 0; ni < 2; ++ni) {
        int m = m0 + wm * 64 + mi * 16 + fq * 4;   // s base (multiple of 4)
        int n = n0 + wn * 32 + ni * 16 + fr;
        int b = m >> 11, s = m & 2047, hh = n >> 6, d = n & 63;
        uint2 pk;
        pk.x = pkbf(acc[z][mi][ni][0] * scle, acc[z][mi][ni][1] * scle);
        pk.y = pkbf(acc[z][mi][ni][2] * scle, acc[z][mi][ni][3] * scle);
        *(uint2*)&o[(((size_t)(b * NHEADS + hh)) * HD + d) * S_LEN + s] = pk;
      }
  }
  // z==1 (K): natural (b,h,s,d) scatter
  {
    unsigned short* o = out + (size_t)QKV_STRIDE;
#pragma unroll
    for (int mi = 0; mi < 4; ++mi)
#pragma unroll
      for (int ni = 0; ni < 2; ++ni)
#pragma unroll
        for (int rg = 0; rg < 4; ++rg) {
          int m = m0 + wm * 64 + mi * 16 + fq * 4 + rg;
          int n = n0 + wn * 32 + ni * 16 + fr;
          int b = m >> 11, s = m & 2047, hh = n >> 6, d = n & 63;
          o[(((size_t)(b * NHEADS + hh)) * S_LEN + s) * HD + d] = f2bf(acc[1][mi][ni][rg]);
        }
  }
}

// ------------- O-projection GEMM, 128x64 tile, dbuf, 2 blocks/CU (frozen at R12) -------------
// R12 win: 1 block/CU -> 2 blocks/CU was -4.5us total.
__global__ __launch_bounds__(256, 3) void gemm128_kernel(
    const unsigned short* __restrict__ A,
    const unsigned short* __restrict__ Bt,
    float* __restrict__ out)
{
  __shared__ unsigned short sA[2 * 128 * 32];   // 16 KB
  __shared__ unsigned short sB[2 * 64 * 32];    // 8 KB
  const int m0 = blockIdx.x * 128;
  const int n0 = blockIdx.y * 64;
  const int t = threadIdx.x;
  const int lane = t & 63;
  const int w = t >> 6;
  const int wm = w & 1, wn = w >> 1;

  const int sr  = lane >> 2;                  // row within 16
  const int scp = lane & 3;                   // physical chunk
  const int scl = scp ^ ((sr >> 1) & 3);      // logical (global) k-chunk
  const long ga0 = (long)(m0 + 16 * w + sr) * HDIM + scl * 8;
  const long ga1 = ga0 + 64l * HDIM;
  const long gb0 = (long)(n0 + 16 * w + sr) * HDIM + scl * 8;

  const int fr = lane & 15;
  const int fq = lane >> 4;
  int offA[4], offB[2];
#pragma unroll
  for (int i = 0; i < 4; ++i) {
    int ra = wm * 64 + i * 16 + fr;
    offA[i] = ra * 32 + (fq ^ ((ra >> 1) & 3)) * 8;
  }
#pragma unroll
  for (int i = 0; i < 2; ++i) {
    int rb = wn * 32 + i * 16 + fr;
    offB[i] = rb * 32 + (fq ^ ((rb >> 1) & 3)) * 8;
  }

  float4v acc[4][2] = {};

  auto stage = [&](int ks) {
    const int kk = ks * 32;
    unsigned short* A0 = &sA[(ks & 1) * 4096 + (16 * w) * 32];
    unsigned short* B0 = &sB[(ks & 1) * 2048 + (16 * w) * 32];
    async_copy16(A + ga0 + kk, A0);
    async_copy16(A + ga1 + kk, A0 + 2048);
    async_copy16(Bt + gb0 + kk, B0);
  };

  stage(0);
#pragma unroll 2
  for (int ks = 0; ks < 32; ++ks) {
    __syncthreads();                 // vmcnt drain -> tile ks resident
    if (ks < 31) stage(ks + 1);      // overlapped with compute below
    const unsigned short* a = &sA[(ks & 1) * 4096];
    const unsigned short* bp = &sB[(ks & 1) * 2048];
    short8 af[4], bf[2];
#pragma unroll
    for (int i = 0; i < 4; ++i) af[i] = *(const short8*)&a[offA[i]];
#pragma unroll
    for (int i = 0; i < 2; ++i) bf[i] = *(const short8*)&bp[offB[i]];
#pragma unroll
    for (int mi = 0; mi < 4; ++mi)
#pragma unroll
      for (int ni = 0; ni < 2; ++ni)
        acc[mi][ni] = __builtin_amdgcn_mfma_f32_16x16x32_bf16(af[mi], bf[ni], acc[mi][ni], 0, 0, 0);
  }

#pragma unroll
  for (int mi = 0; mi < 4; ++mi)
#pragma unroll
    for (int ni = 0; ni < 2; ++ni)
#pragma unroll
      for (int rg = 0; rg < 4; ++rg) {
        int m = m0 + wm * 64 + mi * 16 + fq * 4 + rg;
        int n = n0 + wn * 32 + ni * 16 + fr;
        out[(size_t)m * HDIM + n] = acc[mi][ni][rg];
      }
}

// stage one 64-k tile (K 8 KB + V^T 8 KB) into buffer (tile&1); 2 DMA copies per wave
__device__ __forceinline__ void stage_tile(char* smem, const unsigned short* Kp,
    const unsigned short* Vtp, size_t base, int tile, int w, int kr, int kc) {
  const int kv = tile * 64;
  char* bufb = smem + (tile & 1) * 16384;
  unsigned short* dK = (unsigned short*)bufb + (w * 8) * 64;
  async_copy16(Kp + base + (size_t)(kv + w * 8 + kr) * HD + ((kc ^ kr) * 8), dK);
  unsigned short* dV = (unsigned short*)(bufb + 8192) + (w * 8) * 64;
  const int d = w * 8 + kr;
  async_copy16(Vtp + base + (size_t)d * S_LEN + kv + ((kc ^ kr) * 8), dV);
}

// ---------------- flash attention: split-k waves, fixed-base softmax, ----------------
// ---------------- BN=64 double-buffered staging, ONE barrier per tile ----------------
// R13 delta on the R11/R12 attn (51.5us): l-sum via ones-row MFMA -- the R7-verified
// trick (passed, absmax 2.44e-4) WITHOUT R7's unroll-4 spill. mfma(ones, pf, l_acc)
// computes sum_k P[k][q] on the ~74%-idle matrix pipe (every C row equals the k-sum,
// A=1); removes 12 VALU adds/tile + the 4 end-of-loop shfl_xors. VGPR 64 -> ~76,
// far under the 128 cap -- no spill path (watch WRITE_SIZE stays 8MB).
// Kept: XCD remap (FETCH 70->12.4MB), cvt_pk P-pack (-4us, R9).
__global__ __launch_bounds__(512, 4) void attn_kernel(
    const unsigned short* __restrict__ Qtp,
    const unsigned short* __restrict__ Kp,
    const unsigned short* __restrict__ Vtp,
    const int* __restrict__ mask,
    unsigned short* __restrict__ ctx)
{
  __shared__ __align__(16) char smem[53248];

  // XCD-aware remap: p in [0,512); bh = (p&7)+8*(j>>4), q-tile = j&15, j = p>>3.
  // Bijective: p = (bh&7) + 8*((bh>>3)*16 + qt).
  const int p = blockIdx.x + 16 * blockIdx.y;
  const int j = p >> 3;
  const int bh = (p & 7) + 8 * (j >> 4);
  const int q0 = (j & 15) * 128;

  const int b = bh >> 4;
  const int h = bh & 15;
  const size_t base = (size_t)bh * (S_LEN * HD);
  const int t = threadIdx.x;
  const int lane = t & 63;
  const int w = t >> 6;                        // 0..7
  const int qg = w >> 1;                       // q-group (32 q)
  const int kh = w & 1;                        // k-half (32 k)
  const int fr = lane & 15;
  const int fq = lane >> 4;
  const int kr = lane >> 3, kc = lane & 7;     // staging lane map
  unsigned short* sPw = (unsigned short*)(smem + 32768) + w * (32 * 40);

  // Q fragments (B-operand): 32 q rows, from transposed (b,h,d,s) layout
  short8 qfr[2][2];
#pragma unroll
  for (int q_ = 0; q_ < 2; ++q_)
#pragma unroll
    for (int ks = 0; ks < 2; ++ks)
#pragma unroll
      for (int jj = 0; jj < 8; ++jj)
        qfr[q_][ks][jj] = (short)Qtp[base + (size_t)(ks * 32 + fq * 8 + jj) * S_LEN
                                    + (q0 + qg * 32 + q_ * 16 + fr)];

  // ones A-fragment for the l-sum MFMA (bf16 1.0 = 0x3F80)
  short8 onesv;
#pragma unroll
  for (int jj = 0; jj < 8; ++jj) onesv[jj] = (short)0x3F80;

  float4v o_acc[4][2] = {};                    // [df][q_], partial O^T over this k-half
  float4v l_acc[2] = {};                       // l[q] via ones-MFMA (all C rows equal)
  const float4v zero4 = {0.f, 0.f, 0.f, 0.f};

  // mask prefetch for tile 0 (bit k of ballot = mask[kv0+k] != 0)
  int mnext = mask[b * S_LEN + lane];

  // prologue: stage tile 0 into buffer 0
  stage_tile(smem, Kp, Vtp, base, 0, w, kr, kc);

#pragma unroll 2
  for (int it = 0; it < 32; ++it) {
    __syncthreads();   // drains vmcnt -> tile 'it' resident; buffer (it+1)&1 free
    if (it < 31)
      stage_tile(smem, Kp, Vtp, base, it + 1, w, kr, kc);   // in flight during compute

    unsigned long long bal = __ballot(mnext != 0);
    if (it < 31)
      mnext = mask[b * S_LEN + (it + 1) * 64 + lane];       // prefetch next tile's mask

    const unsigned short* sKb  = (const unsigned short*)(smem + (it & 1) * 16384);
    const unsigned short* sVtb = (const unsigned short*)(smem + (it & 1) * 16384 + 8192);

    // S^T = K · Q^T over this wave's 32-k strip (scores in log2 domain: Q pre-scaled)
    float4v s_acc[2][2];
#pragma unroll
    for (int kf = 0; kf < 2; ++kf) {
      int rk = kh * 32 + kf * 16 + fr;
      short8 k0 = *(const short8*)&sKb[rk * 64 + ((fq ^ (rk & 7)) * 8)];
      short8 k1 = *(const short8*)&sKb[rk * 64 + (((4 + fq) ^ (rk & 7)) * 8)];
#pragma unroll
      for (int q_ = 0; q_ < 2; ++q_) {
        float4v s = __builtin_amdgcn_mfma_f32_16x16x32_bf16(k0, qfr[q_][0], zero4, 0, 0, 0);
        s_acc[kf][q_] = __builtin_amdgcn_mfma_f32_16x16x32_bf16(k1, qfr[q_][1], s, 0, 0, 0);
      }
    }

    // V fragments early: LDS latency overlaps the softmax VALU below
    short8 vf[4];
#pragma unroll
    for (int df = 0; df < 4; ++df) {
      int rv = df * 16 + fr;
      vf[df] = *(const short8*)&sVtb[rv * 64 + (((kh * 4 + fq) ^ (fr & 7)) * 8)];
    }

    // exp2 -> (rare) mask zeroing -> pack P^T strip (cvt_pk; l comes from ones-MFMA)
#pragma unroll
    for (int kf = 0; kf < 2; ++kf) {
      unsigned mseg = 0xFu;
      if (bal != ~0ull)                        // wave-uniform slow path
        mseg = (unsigned)(bal >> (kh * 32 + kf * 16 + fq * 4)) & 0xFu;
#pragma unroll
      for (int q_ = 0; q_ < 2; ++q_) {
        float p0 = __builtin_amdgcn_exp2f(s_acc[kf][q_][0]);
        float p1 = __builtin_amdgcn_exp2f(s_acc[kf][q_][1]);
        float p2 = __builtin_amdgcn_exp2f(s_acc[kf][q_][2]);
        float p3 = __builtin_amdgcn_exp2f(s_acc[kf][q_][3]);
        if (bal != ~0ull) {
          p0 = (mseg & 1u) ? p0 : 0.f;
          p1 = (mseg & 2u) ? p1 : 0.f;
          p2 = (mseg & 4u) ? p2 : 0.f;
          p3 = (mseg & 8u) ? p3 : 0.f;
        }
        uint2 pk;
        pk.x = cvtpk(p0, p1);
        pk.y = cvtpk(p2, p3);
        *(uint2*)&sPw[(q_ * 16 + fr) * 40 + (kf * 4 + fq) * 4] = pk;
      }
    }
    // no barrier: sP strip is per-wave; LDS ops are in-order within a wave

    // O^T += V^T · P^T; l += ones · P^T over this wave's 32-k strip
    short8 pf[2];
#pragma unroll
    for (int q_ = 0; q_ < 2; ++q_)
      pf[q_] = *(const short8*)&sPw[(q_ * 16 + fr) * 40 + fq * 8];
#pragma unroll
    for (int df = 0; df < 4; ++df)
#pragma unroll
      for (int q_ = 0; q_ < 2; ++q_)
        o_acc[df][q_] = __builtin_amdgcn_mfma_f32_16x16x32_bf16(vf[df], pf[q_], o_acc[df][q_], 0, 0, 0);
#pragma unroll
    for (int q_ = 0; q_ < 2; ++q_)
      l_acc[q_] = __builtin_amdgcn_mfma_f32_16x16x32_bf16(onesv, pf[q_], l_acc[q_], 0, 0, 0);
  }

  // l[q=fr] = l_acc[q_][any]: every C row of the ones-MFMA equals sum_k P[k][q].
  // No cross-lane reduction needed (replaces 2x shfl_xor per q_).
  float l_lane[2] = { l_acc[0][0], l_acc[1][0] };

  // cross-wave-pair (kh) reduction via LDS.
  // Record: 32 O floats + 2 l floats, stride 34 (136 B). 4 pairs x 64 lanes x 136 B
  // = 34816 B, aliasing the dbuf + wave-0's P strip (all dead after the barrier).
  __syncthreads();   // all waves done with buffers/strips before aliasing
  float* red = (float*)smem;
  float* rec = red + (size_t)(qg * 64 + lane) * 34;
  if (kh) {
#pragma unroll
    for (int df = 0; df < 4; ++df)
#pragma unroll
      for (int q_ = 0; q_ < 2; ++q_) {
        int e = df * 2 + q_;
        *(float2*)&rec[4 * e]     = make_float2(o_acc[df][q_][0], o_acc[df][q_][1]);
        *(float2*)&rec[4 * e + 2] = make_float2(o_acc[df][q_][2], o_acc[df][q_][3]);
      }
    *(float2*)&rec[32] = make_float2(l_lane[0], l_lane[1]);
  }
  __syncthreads();
  if (!kh) {
#pragma unroll
    for (int df = 0; df < 4; ++df)
#pragma unroll
      for (int q_ = 0; q_ < 2; ++q_) {
        int e = df * 2 + q_;
        float2 a = *(float2*)&rec[4 * e];
        float2 c = *(float2*)&rec[4 * e + 2];
        o_acc[df][q_][0] += a.x; o_acc[df][q_][1] += a.y;
        o_acc[df][q_][2] += c.x; o_acc[df][q_][3] += c.y;
      }
    float2 lr = *(float2*)&rec[32];
    float inv_l[2];
    inv_l[0] = 1.0f / (l_lane[0] + lr.x);
    inv_l[1] = 1.0f / (l_lane[1] + lr.y);
    // epilogue: O^T C-layout -> 4 consecutive d per lane -> packed 8B stores
#pragma unroll
    for (int q_ = 0; q_ < 2; ++q_) {
      size_t rowoff = ((size_t)(b * S_LEN + q0 + qg * 32 + q_ * 16 + fr)) * HDIM + h * HD;
#pragma unroll
      for (int df = 0; df < 4; ++df) {
        uint2 pk;
        pk.x = pkbf(o_acc[df][q_][0] * inv_l[q_], o_acc[df][q_][1] * inv_l[q_]);
        pk.y = pkbf(o_acc[df][q_][2] * inv_l[q_], o_acc[df][q_][3] * inv_l[q_]);
        *(uint2*)&ctx[rowoff + df * 16 + fq * 4] = pk;
      }
    }
  }
}

extern "C" void kernel_launch(void* const* d_in, const int* in_sizes, int n_in,
                              void* d_out, int out_size, void* d_ws, size_t ws_size,
                              hipStream_t stream) {
  const float* X  = (const float*)d_in[0];
  const int* mask = (const int*)d_in[1];
  const float* Wq = (const float*)d_in[2];
  const float* Wk = (const float*)d_in[3];
  const float* Wv = (const float*)d_in[4];
  const float* Wo = (const float*)d_in[5];
  float* out = (float*)d_out;

  char* ws = (char*)d_ws;
  // layout (40 MB): [0,8M) Xb then reused as CTX; [8M,16M) Wt x4; [16M,40M) Q^T,K,V^T bf16
  unsigned short* Xb  = (unsigned short*)(ws);
  unsigned short* Wt  = (unsigned short*)(ws + (8u << 20));
  unsigned short* QKV = (unsigned short*)(ws + (16u << 20));
  unsigned short* CTX = (unsigned short*)(ws);   // reuse Xb region (dead after QKV GEMM)

  prep_kernel<<<5120, 256, 0, stream>>>(X, Xb, Wq, Wk, Wv, Wo, Wt);
  gemm_qkv_kernel<<<dim3(32, 16), 256, 0, stream>>>(Xb, Wt, QKV);
  attn_kernel<<<dim3(16, 32), 512, 0, stream>>>(
      QKV, QKV + QKV_STRIDE, QKV + 2 * (size_t)QKV_STRIDE, mask, CTX);
  gemm128_kernel<<<dim3(32, 16), 256, 0, stream>>>(CTX, Wt + (3u << 20), out);
}

// Round 14
// 175.971 us; speedup vs baseline: 1.2395x; 1.0237x over previous
//
#include <hip/hip_runtime.h>
#include <hip/hip_bf16.h>

#define S_LEN 2048
#define HDIM  1024
#define NHEADS 16
#define HD    64
#define QKV_STRIDE (S_LEN * 2 * HDIM)   // 4194304 elements per tensor

typedef __attribute__((ext_vector_type(8))) short short8;
typedef __attribute__((ext_vector_type(4))) float float4v;

// cheap bf16 convert: round-half-up (bias ~2^-24 rel, negligible vs bf16 eps)
__device__ __forceinline__ unsigned short f2bf(float f) {
  return (unsigned short)((__builtin_bit_cast(unsigned int, f) + 0x8000u) >> 16);
}
// pack two floats -> two bf16 in one u32 via v_perm_b32 (3 VALU ops)
__device__ __forceinline__ unsigned int pkbf(float a, float b) {
  unsigned int ua = __builtin_bit_cast(unsigned int, a) + 0x8000u;
  unsigned int ub = __builtin_bit_cast(unsigned int, b) + 0x8000u;
  return __builtin_amdgcn_perm(ub, ua, 0x07060302u);  // {ub.hi16, ua.hi16}
}
// pack two floats -> two bf16 in ONE VALU op (RNE). Numerics proven in R1/R9/R11/R13.
__device__ __forceinline__ unsigned int cvtpk(float a, float b) {
  unsigned int r;
  asm("v_cvt_pk_bf16_f32 %0, %1, %2" : "=v"(r) : "v"(a), "v"(b));
  return r;
}

__device__ __forceinline__ void async_copy16(const void* g, void* l) {
  __builtin_amdgcn_global_load_lds((__attribute__((address_space(1))) const void*)g,
                                   (__attribute__((address_space(3))) void*)l, 16, 0, 0);
}

// ---------------- fused prep: cast X (fp32->bf16) + transpose/cast weights ----------------
// blocks [0,4096): X cast, 4 elems/thread. blocks [4096,5120): W transpose tiles.
__global__ void prep_kernel(const float* __restrict__ X, unsigned short* __restrict__ Xb,
                            const float* __restrict__ W0, const float* __restrict__ W1,
                            const float* __restrict__ W2, const float* __restrict__ W3,
                            unsigned short* __restrict__ Wt) {
  __shared__ unsigned short tile[64][72];   // [n_loc][k_loc], padded (trans branch only)
  const int t = threadIdx.x;
  if (blockIdx.x < 4096) {
    int i = blockIdx.x * 256 + t;          // 0 .. 1048575 float4 chunks
    float4 v = ((const float4*)X)[i];
    uint2 o;
    o.x = pkbf(v.x, v.y);
    o.y = pkbf(v.z, v.w);
    ((uint2*)Xb)[i] = o;
    return;
  }
  const int wid = blockIdx.x - 4096;       // 0..1023
  const int z = wid >> 8;                  // 0..3
  const int rem = wid & 255;
  const int n0 = (rem & 15) * 64;
  const int k0 = (rem >> 4) * 64;
  const float* W = (z == 0) ? W0 : (z == 1) ? W1 : (z == 2) ? W2 : W3;
  unsigned short* out = Wt + (size_t)z * HDIM * HDIM;
#pragma unroll
  for (int it = 0; it < 4; ++it) {
    int idx = it * 256 + t;          // 1024 float4 chunks
    int r  = idx >> 4;               // k_loc 0..63
    int c4 = (idx & 15) * 4;         // n_loc
    float4 v = *(const float4*)&W[(size_t)(k0 + r) * HDIM + n0 + c4];
    tile[c4 + 0][r] = f2bf(v.x);
    tile[c4 + 1][r] = f2bf(v.y);
    tile[c4 + 2][r] = f2bf(v.z);
    tile[c4 + 3][r] = f2bf(v.w);
  }
  __syncthreads();
#pragma unroll
  for (int it = 0; it < 4; ++it) {
    int idx = it * 256 + t;
    int r  = idx >> 4;               // n_loc
    int c4 = (idx & 15) * 4;         // k_loc
    ushort4 o;
    o.x = tile[r][c4 + 0]; o.y = tile[r][c4 + 1];
    o.z = tile[r][c4 + 2]; o.w = tile[r][c4 + 3];
    *(ushort4*)&out[(size_t)(n0 + r) * HDIM + k0 + c4] = o;
  }
}

// ---------------- fused QKV GEMM, 128x64 tile, BK=64, DOUBLE-BUFFERED (R14) ----------------
// R14: K-step 32 -> 64. Both GEMMs are GRID-limited at 2 blocks/CU, so doubling LDS
// (40 -> 80 KB) costs zero occupancy -- unlike the guide's m132 BK=128 failure. Barrier
// count halves (32 -> 16); MFMA per vmcnt(0)+barrier drain doubles (24 -> 48/wave),
// amortizing the structural ~20% drain stall. Each 64-k stage = two proven 32-k stages
// into stacked sub-tiles; fragment formulas unchanged (sub-tile base + h2*4096/6144).
__global__ __launch_bounds__(256, 2) void gemm_qkv_kernel(
    const unsigned short* __restrict__ A,
    const unsigned short* __restrict__ Wt,   // 3 B^T matrices, 1M elements apart
    unsigned short* __restrict__ out)
{
  __shared__ unsigned short sA[2 * 2 * 128 * 32];      // 32 KB (dbuf x 2 sub-tiles)
  __shared__ unsigned short sB[2 * 2 * 3 * 64 * 32];   // 48 KB
  const int m0 = blockIdx.x * 128;
  const int n0 = blockIdx.y * 64;
  const int t = threadIdx.x;
  const int lane = t & 63;
  const int w = t >> 6;
  const int wm = w & 1, wn = w >> 1;

  const int sr  = lane >> 2;                  // row within 16
  const int scp = lane & 3;                   // physical chunk
  const int scl = scp ^ ((sr >> 1) & 3);      // logical (global) k-chunk
  const long ga0 = (long)(m0 + 16 * w + sr) * HDIM + scl * 8;
  const long ga1 = ga0 + 64l * HDIM;
  const long gb  = (long)(n0 + 16 * w + sr) * HDIM + scl * 8;

  const int fr = lane & 15;
  const int fq = lane >> 4;
  int offA[4], offB[2];
#pragma unroll
  for (int i = 0; i < 4; ++i) {
    int ra = wm * 64 + i * 16 + fr;
    offA[i] = ra * 32 + (fq ^ ((ra >> 1) & 3)) * 8;
  }
#pragma unroll
  for (int i = 0; i < 2; ++i) {
    int rb = wn * 32 + i * 16 + fr;
    offB[i] = rb * 32 + (fq ^ ((rb >> 1) & 3)) * 8;
  }

  float4v acc[3][4][2] = {};

  // stage one 64-k step (two 32-k sub-tiles) into buffer ks&1 (10 copies per wave)
  auto stage = [&](int ks) {
#pragma unroll
    for (int h2 = 0; h2 < 2; ++h2) {
      const int kk = ks * 64 + h2 * 32;
      unsigned short* A0 = &sA[(ks & 1) * 8192 + h2 * 4096 + (16 * w) * 32];
      unsigned short* Bb = &sB[(ks & 1) * 12288 + h2 * 6144 + (16 * w) * 32];
      async_copy16(A + ga0 + kk, A0);
      async_copy16(A + ga1 + kk, A0 + 2048);
#pragma unroll
      for (int z = 0; z < 3; ++z)
        async_copy16(Wt + (long)z * (HDIM * HDIM) + gb + kk, Bb + z * 2048);
    }
  };

  stage(0);
#pragma unroll 2
  for (int ks = 0; ks < 16; ++ks) {
    __syncthreads();                 // vmcnt drain -> 64-k step ks resident
    if (ks < 15) stage(ks + 1);      // in flight during compute below
#pragma unroll
    for (int h2 = 0; h2 < 2; ++h2) {
      const unsigned short* a  = &sA[(ks & 1) * 8192 + h2 * 4096];
      const unsigned short* bb = &sB[(ks & 1) * 12288 + h2 * 6144];
      short8 af[4];
#pragma unroll
      for (int i = 0; i < 4; ++i) af[i] = *(const short8*)&a[offA[i]];
#pragma unroll
      for (int z = 0; z < 3; ++z) {
        short8 b0 = *(const short8*)&bb[z * 2048 + offB[0]];
        short8 b1 = *(const short8*)&bb[z * 2048 + offB[1]];
#pragma unroll
        for (int mi = 0; mi < 4; ++mi) {
          acc[z][mi][0] = __builtin_amdgcn_mfma_f32_16x16x32_bf16(af[mi], b0, acc[z][mi][0], 0, 0, 0);
          acc[z][mi][1] = __builtin_amdgcn_mfma_f32_16x16x32_bf16(af[mi], b1, acc[z][mi][1], 0, 0, 0);
        }
      }
    }
  }

  // ---- epilogues ----
  // z==0 (Q^T, scaled) and z==2 (V^T): packed (b,h,d,s)
#pragma unroll
  for (int z = 0; z < 3; z += 2) {
    const float scle = (z == 0) ? 0.18033688011112042f : 1.0f;
    unsigned short* o = out + (size_t)z * QKV_STRIDE;
#pragma unroll
    for (int mi = 0; mi < 4; ++mi)
#pragma unroll
      for (int ni = 0; ni < 2; ++ni) {
        int m = m0 + wm * 64 + mi * 16 + fq * 4;   // s base (multiple of 4)
        int n = n0 + wn * 32 + ni * 16 + fr;
        int b = m >> 11, s = m & 2047, hh = n >> 6, d = n & 63;
        uint2 pk;
        pk.x = pkbf(acc[z][mi][ni][0] * scle, acc[z][mi][ni][1] * scle);
        pk.y = pkbf(acc[z][mi][ni][2] * scle, acc[z][mi][ni][3] * scle);
        *(uint2*)&o[(((size_t)(b * NHEADS + hh)) * HD + d) * S_LEN + s] = pk;
      }
  }
  // z==1 (K): natural (b,h,s,d) scatter
  {
    unsigned short* o = out + (size_t)QKV_STRIDE;
#pragma unroll
    for (int mi = 0; mi < 4; ++mi)
#pragma unroll
      for (int ni = 0; ni < 2; ++ni)
#pragma unroll
        for (int rg = 0; rg < 4; ++rg) {
          int m = m0 + wm * 64 + mi * 16 + fq * 4 + rg;
          int n = n0 + wn * 32 + ni * 16 + fr;
          int b = m >> 11, s = m & 2047, hh = n >> 6, d = n & 63;
          o[(((size_t)(b * NHEADS + hh)) * S_LEN + s) * HD + d] = f2bf(acc[1][mi][ni][rg]);
        }
  }
}

// ------------- O-projection GEMM, 128x64 tile, BK=64, dbuf, 2 blocks/CU (R14) -------------
// Same BK=32 -> 64 transformation; LDS 24 -> 48 KB (grid-limited 2/CU, no occupancy cost).
// Barriers 32 -> 16; 16 MFMA per drain per wave (was 8).
__global__ __launch_bounds__(256, 3) void gemm128_kernel(
    const unsigned short* __restrict__ A,
    const unsigned short* __restrict__ Bt,
    float* __restrict__ out)
{
  __shared__ unsigned short sA[2 * 2 * 128 * 32];   // 32 KB
  __shared__ unsigned short sB[2 * 2 * 64 * 32];    // 16 KB
  const int m0 = blockIdx.x * 128;
  const int n0 = blockIdx.y * 64;
  const int t = threadIdx.x;
  const int lane = t & 63;
  const int w = t >> 6;
  const int wm = w & 1, wn = w >> 1;

  const int sr  = lane >> 2;                  // row within 16
  const int scp = lane & 3;                   // physical chunk
  const int scl = scp ^ ((sr >> 1) & 3);      // logical (global) k-chunk
  const long ga0 = (long)(m0 + 16 * w + sr) * HDIM + scl * 8;
  const long ga1 = ga0 + 64l * HDIM;
  const long gb0 = (long)(n0 + 16 * w + sr) * HDIM + scl * 8;

  const int fr = lane & 15;
  const int fq = lane >> 4;
  int offA[4], offB[2];
#pragma unroll
  for (int i = 0; i < 4; ++i) {
    int ra = wm * 64 + i * 16 + fr;
    offA[i] = ra * 32 + (fq ^ ((ra >> 1) & 3)) * 8;
  }
#pragma unroll
  for (int i = 0; i < 2; ++i) {
    int rb = wn * 32 + i * 16 + fr;
    offB[i] = rb * 32 + (fq ^ ((rb >> 1) & 3)) * 8;
  }

  float4v acc[4][2] = {};

  auto stage = [&](int ks) {
#pragma unroll
    for (int h2 = 0; h2 < 2; ++h2) {
      const int kk = ks * 64 + h2 * 32;
      unsigned short* A0 = &sA[(ks & 1) * 8192 + h2 * 4096 + (16 * w) * 32];
      unsigned short* B0 = &sB[(ks & 1) * 4096 + h2 * 2048 + (16 * w) * 32];
      async_copy16(A + ga0 + kk, A0);
      async_copy16(A + ga1 + kk, A0 + 2048);
      async_copy16(Bt + gb0 + kk, B0);
    }
  };

  stage(0);
#pragma unroll 2
  for (int ks = 0; ks < 16; ++ks) {
    __syncthreads();                 // vmcnt drain -> 64-k step ks resident
    if (ks < 15) stage(ks + 1);      // overlapped with compute below
#pragma unroll
    for (int h2 = 0; h2 < 2; ++h2) {
      const unsigned short* a = &sA[(ks & 1) * 8192 + h2 * 4096];
      const unsigned short* bp = &sB[(ks & 1) * 4096 + h2 * 2048];
      short8 af[4], bf[2];
#pragma unroll
      for (int i = 0; i < 4; ++i) af[i] = *(const short8*)&a[offA[i]];
#pragma unroll
      for (int i = 0; i < 2; ++i) bf[i] = *(const short8*)&bp[offB[i]];
#pragma unroll
      for (int mi = 0; mi < 4; ++mi)
#pragma unroll
        for (int ni = 0; ni < 2; ++ni)
          acc[mi][ni] = __builtin_amdgcn_mfma_f32_16x16x32_bf16(af[mi], bf[ni], acc[mi][ni], 0, 0, 0);
    }
  }

#pragma unroll
  for (int mi = 0; mi < 4; ++mi)
#pragma unroll
    for (int ni = 0; ni < 2; ++ni)
#pragma unroll
      for (int rg = 0; rg < 4; ++rg) {
        int m = m0 + wm * 64 + mi * 16 + fq * 4 + rg;
        int n = n0 + wn * 32 + ni * 16 + fr;
        out[(size_t)m * HDIM + n] = acc[mi][ni][rg];
      }
}

// stage one 64-k tile (K 8 KB + V^T 8 KB) into buffer (tile&1); 2 DMA copies per wave
__device__ __forceinline__ void stage_tile(char* smem, const unsigned short* Kp,
    const unsigned short* Vtp, size_t base, int tile, int w, int kr, int kc) {
  const int kv = tile * 64;
  char* bufb = smem + (tile & 1) * 16384;
  unsigned short* dK = (unsigned short*)bufb + (w * 8) * 64;
  async_copy16(Kp + base + (size_t)(kv + w * 8 + kr) * HD + ((kc ^ kr) * 8), dK);
  unsigned short* dV = (unsigned short*)(bufb + 8192) + (w * 8) * 64;
  const int d = w * 8 + kr;
  async_copy16(Vtp + base + (size_t)d * S_LEN + kv + ((kc ^ kr) * 8), dV);
}

// ---------------- flash attention: split-k waves, fixed-base softmax, ----------------
// ---------------- BN=64 double-buffered staging, ONE barrier per tile ----------------
// Frozen at R13 (timing-best; absmax 2.44e-4): XCD remap + cvt_pk P-pack + ones-MFMA
// l-sum (VALU 45->39 measured; R13 profiling pass ran at ~9% lower clock, ratios
// confirm the mechanism).
__global__ __launch_bounds__(512, 4) void attn_kernel(
    const unsigned short* __restrict__ Qtp,
    const unsigned short* __restrict__ Kp,
    const unsigned short* __restrict__ Vtp,
    const int* __restrict__ mask,
    unsigned short* __restrict__ ctx)
{
  __shared__ __align__(16) char smem[53248];

  // XCD-aware remap: p in [0,512); bh = (p&7)+8*(j>>4), q-tile = j&15, j = p>>3.
  // Bijective: p = (bh&7) + 8*((bh>>3)*16 + qt).
  const int p = blockIdx.x + 16 * blockIdx.y;
  const int j = p >> 3;
  const int bh = (p & 7) + 8 * (j >> 4);
  const int q0 = (j & 15) * 128;

  const int b = bh >> 4;
  const int h = bh & 15;
  const size_t base = (size_t)bh * (S_LEN * HD);
  const int t = threadIdx.x;
  const int lane = t & 63;
  const int w = t >> 6;                        // 0..7
  const int qg = w >> 1;                       // q-group (32 q)
  const int kh = w & 1;                        // k-half (32 k)
  const int fr = lane & 15;
  const int fq = lane >> 4;
  const int kr = lane >> 3, kc = lane & 7;     // staging lane map
  unsigned short* sPw = (unsigned short*)(smem + 32768) + w * (32 * 40);

  // Q fragments (B-operand): 32 q rows, from transposed (b,h,d,s) layout
  short8 qfr[2][2];
#pragma unroll
  for (int q_ = 0; q_ < 2; ++q_)
#pragma unroll
    for (int ks = 0; ks < 2; ++ks)
#pragma unroll
      for (int jj = 0; jj < 8; ++jj)
        qfr[q_][ks][jj] = (short)Qtp[base + (size_t)(ks * 32 + fq * 8 + jj) * S_LEN
                                    + (q0 + qg * 32 + q_ * 16 + fr)];

  // ones A-fragment for the l-sum MFMA (bf16 1.0 = 0x3F80)
  short8 onesv;
#pragma unroll
  for (int jj = 0; jj < 8; ++jj) onesv[jj] = (short)0x3F80;

  float4v o_acc[4][2] = {};                    // [df][q_], partial O^T over this k-half
  float4v l_acc[2] = {};                       // l[q] via ones-MFMA (all C rows equal)
  const float4v zero4 = {0.f, 0.f, 0.f, 0.f};

  // mask prefetch for tile 0 (bit k of ballot = mask[kv0+k] != 0)
  int mnext = mask[b * S_LEN + lane];

  // prologue: stage tile 0 into buffer 0
  stage_tile(smem, Kp, Vtp, base, 0, w, kr, kc);

#pragma unroll 2
  for (int it = 0; it < 32; ++it) {
    __syncthreads();   // drains vmcnt -> tile 'it' resident; buffer (it+1)&1 free
    if (it < 31)
      stage_tile(smem, Kp, Vtp, base, it + 1, w, kr, kc);   // in flight during compute

    unsigned long long bal = __ballot(mnext != 0);
    if (it < 31)
      mnext = mask[b * S_LEN + (it + 1) * 64 + lane];       // prefetch next tile's mask

    const unsigned short* sKb  = (const unsigned short*)(smem + (it & 1) * 16384);
    const unsigned short* sVtb = (const unsigned short*)(smem + (it & 1) * 16384 + 8192);

    // S^T = K · Q^T over this wave's 32-k strip (scores in log2 domain: Q pre-scaled)
    float4v s_acc[2][2];
#pragma unroll
    for (int kf = 0; kf < 2; ++kf) {
      int rk = kh * 32 + kf * 16 + fr;
      short8 k0 = *(const short8*)&sKb[rk * 64 + ((fq ^ (rk & 7)) * 8)];
      short8 k1 = *(const short8*)&sKb[rk * 64 + (((4 + fq) ^ (rk & 7)) * 8)];
#pragma unroll
      for (int q_ = 0; q_ < 2; ++q_) {
        float4v s = __builtin_amdgcn_mfma_f32_16x16x32_bf16(k0, qfr[q_][0], zero4, 0, 0, 0);
        s_acc[kf][q_] = __builtin_amdgcn_mfma_f32_16x16x32_bf16(k1, qfr[q_][1], s, 0, 0, 0);
      }
    }

    // V fragments early: LDS latency overlaps the softmax VALU below
    short8 vf[4];
#pragma unroll
    for (int df = 0; df < 4; ++df) {
      int rv = df * 16 + fr;
      vf[df] = *(const short8*)&sVtb[rv * 64 + (((kh * 4 + fq) ^ (fr & 7)) * 8)];
    }

    // exp2 -> (rare) mask zeroing -> pack P^T strip (cvt_pk; l comes from ones-MFMA)
#pragma unroll
    for (int kf = 0; kf < 2; ++kf) {
      unsigned mseg = 0xFu;
      if (bal != ~0ull)                        // wave-uniform slow path
        mseg = (unsigned)(bal >> (kh * 32 + kf * 16 + fq * 4)) & 0xFu;
#pragma unroll
      for (int q_ = 0; q_ < 2; ++q_) {
        float p0 = __builtin_amdgcn_exp2f(s_acc[kf][q_][0]);
        float p1 = __builtin_amdgcn_exp2f(s_acc[kf][q_][1]);
        float p2 = __builtin_amdgcn_exp2f(s_acc[kf][q_][2]);
        float p3 = __builtin_amdgcn_exp2f(s_acc[kf][q_][3]);
        if (bal != ~0ull) {
          p0 = (mseg & 1u) ? p0 : 0.f;
          p1 = (mseg & 2u) ? p1 : 0.f;
          p2 = (mseg & 4u) ? p2 : 0.f;
          p3 = (mseg & 8u) ? p3 : 0.f;
        }
        uint2 pk;
        pk.x = cvtpk(p0, p1);
        pk.y = cvtpk(p2, p3);
        *(uint2*)&sPw[(q_ * 16 + fr) * 40 + (kf * 4 + fq) * 4] = pk;
      }
    }
    // no barrier: sP strip is per-wave; LDS ops are in-order within a wave

    // O^T += V^T · P^T; l += ones · P^T over this wave's 32-k strip
    short8 pf[2];
#pragma unroll
    for (int q_ = 0; q_ < 2; ++q_)
      pf[q_] = *(const short8*)&sPw[(q_ * 16 + fr) * 40 + fq * 8];
#pragma unroll
    for (int df = 0; df < 4; ++df)
#pragma unroll
      for (int q_ = 0; q_ < 2; ++q_)
        o_acc[df][q_] = __builtin_amdgcn_mfma_f32_16x16x32_bf16(vf[df], pf[q_], o_acc[df][q_], 0, 0, 0);
#pragma unroll
    for (int q_ = 0; q_ < 2; ++q_)
      l_acc[q_] = __builtin_amdgcn_mfma_f32_16x16x32_bf16(onesv, pf[q_], l_acc[q_], 0, 0, 0);
  }

  // l[q=fr] = l_acc[q_][any]: every C row of the ones-MFMA equals sum_k P[k][q].
  float l_lane[2] = { l_acc[0][0], l_acc[1][0] };

  // cross-wave-pair (kh) reduction via LDS.
  // Record: 32 O floats + 2 l floats, stride 34 (136 B). 4 pairs x 64 lanes x 136 B
  // = 34816 B, aliasing the dbuf + wave-0's P strip (all dead after the barrier).
  __syncthreads();   // all waves done with buffers/strips before aliasing
  float* red = (float*)smem;
  float* rec = red + (size_t)(qg * 64 + lane) * 34;
  if (kh) {
#pragma unroll
    for (int df = 0; df < 4; ++df)
#pragma unroll
      for (int q_ = 0; q_ < 2; ++q_) {
        int e = df * 2 + q_;
        *(float2*)&rec[4 * e]     = make_float2(o_acc[df][q_][0], o_acc[df][q_][1]);
        *(float2*)&rec[4 * e + 2] = make_float2(o_acc[df][q_][2], o_acc[df][q_][3]);
      }
    *(float2*)&rec[32] = make_float2(l_lane[0], l_lane[1]);
  }
  __syncthreads();
  if (!kh) {
#pragma unroll
    for (int df = 0; df < 4; ++df)
#pragma unroll
      for (int q_ = 0; q_ < 2; ++q_) {
        int e = df * 2 + q_;
        float2 a = *(float2*)&rec[4 * e];
        float2 c = *(float2*)&rec[4 * e + 2];
        o_acc[df][q_][0] += a.x; o_acc[df][q_][1] += a.y;
        o_acc[df][q_][2] += c.x; o_acc[df][q_][3] += c.y;
      }
    float2 lr = *(float2*)&rec[32];
    float inv_l[2];
    inv_l[0] = 1.0f / (l_lane[0] + lr.x);
    inv_l[1] = 1.0f / (l_lane[1] + lr.y);
    // epilogue: O^T C-layout -> 4 consecutive d per lane -> packed 8B stores
#pragma unroll
    for (int q_ = 0; q_ < 2; ++q_) {
      size_t rowoff = ((size_t)(b * S_LEN + q0 + qg * 32 + q_ * 16 + fr)) * HDIM + h * HD;
#pragma unroll
      for (int df = 0; df < 4; ++df) {
        uint2 pk;
        pk.x = pkbf(o_acc[df][q_][0] * inv_l[q_], o_acc[df][q_][1] * inv_l[q_]);
        pk.y = pkbf(o_acc[df][q_][2] * inv_l[q_], o_acc[df][q_][3] * inv_l[q_]);
        *(uint2*)&ctx[rowoff + df * 16 + fq * 4] = pk;
      }
    }
  }
}

extern "C" void kernel_launch(void* const* d_in, const int* in_sizes, int n_in,
                              void* d_out, int out_size, void* d_ws, size_t ws_size,
                              hipStream_t stream) {
  const float* X  = (const float*)d_in[0];
  const int* mask = (const int*)d_in[1];
  const float* Wq = (const float*)d_in[2];
  const float* Wk = (const float*)d_in[3];
  const float* Wv = (const float*)d_in[4];
  const float* Wo = (const float*)d_in[5];
  float* out = (float*)d_out;

  char* ws = (char*)d_ws;
  // layout (40 MB): [0,8M) Xb then reused as CTX; [8M,16M) Wt x4; [16M,40M) Q^T,K,V^T bf16
  unsigned short* Xb  = (unsigned short*)(ws);
  unsigned short* Wt  = (unsigned short*)(ws + (8u << 20));
  unsigned short* QKV = (unsigned short*)(ws + (16u << 20));
  unsigned short* CTX = (unsigned short*)(ws);   // reuse Xb region (dead after QKV GEMM)

  prep_kernel<<<5120, 256, 0, stream>>>(X, Xb, Wq, Wk, Wv, Wo, Wt);
  gemm_qkv_kernel<<<dim3(32, 16), 256, 0, stream>>>(Xb, Wt, QKV);
  attn_kernel<<<dim3(16, 32), 512, 0, stream>>>(
      QKV, QKV + QKV_STRIDE, QKV + 2 * (size_t)QKV_STRIDE, mask, CTX);
  gemm128_kernel<<<dim3(32, 16), 256, 0, stream>>>(CTX, Wt + (3u << 20), out);
}